// Round 3
// baseline (1438.445 us; speedup 1.0000x reference)
//
#include <hip/hip_runtime.h>
#include <math.h>

#define B_ 32
#define L_ 512
#define NTOK 16384      // B_*L_
#define NL_ 3
#define H_ 8
#define DK_ 25
#define DV_ 25
#define DM_ 200
#define DFF_ 800
#define QKVD 600        // H_*DK_*3
#define WD_ 150
#define TD_ 50

__device__ __forceinline__ float wave_sum(float v) {
#pragma unroll
  for (int off = 32; off > 0; off >>= 1) v += __shfl_xor(v, off, 64);
  return v;
}

// ---------------- embedding + bias + positional ----------------
__global__ __launch_bounds__(256) void embed_kernel(
    const float* __restrict__ we, const float* __restrict__ ee, const float* __restrict__ te,
    const float* __restrict__ pt, const float* __restrict__ bias,
    const int* __restrict__ wseq, const int* __restrict__ eseq, const int* __restrict__ tseq,
    const int* __restrict__ pseq, float* __restrict__ x) {
  int t = blockIdx.x * 4 + (threadIdx.x >> 6);
  int lane = threadIdx.x & 63;
  const float* wr = we + (size_t)wseq[t] * WD_;
  const float* er = ee + (size_t)eseq[t] * WD_;
  const float* tr = te + (size_t)tseq[t] * TD_;
  const float* pr = pt + (size_t)pseq[t] * DM_;
  float* xr = x + (size_t)t * DM_;
#pragma unroll
  for (int d0 = 0; d0 < DM_; d0 += 64) {
    int d = d0 + lane;
    if (d < DM_) {
      float v = (d < WD_) ? (wr[d] + er[d]) : tr[d - WD_];
      xr[d] = v + bias[d] + pr[d];
    }
  }
}

// ---------------- pack w_qs/w_ks/w_vs -> [NL][600][200] row-major (out-feature, in-dim) ----
__global__ __launch_bounds__(256) void repack_qkv_kernel(
    const float* __restrict__ wq, const float* __restrict__ wk, const float* __restrict__ wv,
    float* __restrict__ Wp) {
  int idx = blockIdx.x * 256 + threadIdx.x;
  if (idx >= NL_ * QKVD * DM_) return;
  int d = idx % DM_;
  int c = (idx / DM_) % QKVD;
  int i = idx / (DM_ * QKVD);
  const float* src = wq; int cc = c;
  if (c >= 400)      { src = wv; cc = c - 400; }
  else if (c >= 200) { src = wk; cc = c - 200; }
  int h = cc / DK_, kk = cc % DK_;
  Wp[idx] = src[(((size_t)i * H_ + h) * DM_ + d) * DK_ + kk];
}

// ---------------- C[N,M] = A[N,K] * W[M,K]^T + bias, optional relu ----------------
#define GBM 64
#define GBN 64
#define GBK 16
__global__ __launch_bounds__(256) void gemm_bias_kernel(
    const float* __restrict__ A, const float* __restrict__ W,
    const float* __restrict__ bias, float* __restrict__ C,
    int M, int K, int do_relu) {
  __shared__ float As[GBK][GBM + 4];
  __shared__ float Ws[GBK][GBN + 4];
  int row0 = blockIdx.x * GBM;
  int col0 = blockIdx.y * GBN;
  int tid = threadIdx.x;
  int tx = tid & 15, ty = tid >> 4;
  int tA = tid >> 2, kqA = tid & 3;
  float acc[4][4] = {};
  for (int k0 = 0; k0 < K; k0 += GBK) {
    int k = k0 + kqA * 4;
    float4 av = make_float4(0.f, 0.f, 0.f, 0.f);
    if (k + 3 < K)
      av = *reinterpret_cast<const float4*>(A + (size_t)(row0 + tA) * K + k);
    As[kqA * 4 + 0][tA] = av.x;
    As[kqA * 4 + 1][tA] = av.y;
    As[kqA * 4 + 2][tA] = av.z;
    As[kqA * 4 + 3][tA] = av.w;
    float4 wv = make_float4(0.f, 0.f, 0.f, 0.f);
    if ((col0 + tA) < M && k + 3 < K)
      wv = *reinterpret_cast<const float4*>(W + (size_t)(col0 + tA) * K + k);
    Ws[kqA * 4 + 0][tA] = wv.x;
    Ws[kqA * 4 + 1][tA] = wv.y;
    Ws[kqA * 4 + 2][tA] = wv.z;
    Ws[kqA * 4 + 3][tA] = wv.w;
    __syncthreads();
#pragma unroll
    for (int kk = 0; kk < GBK; ++kk) {
      float4 a4 = *reinterpret_cast<const float4*>(&As[kk][ty * 4]);
      float4 w4 = *reinterpret_cast<const float4*>(&Ws[kk][tx * 4]);
      float a[4] = {a4.x, a4.y, a4.z, a4.w};
      float w[4] = {w4.x, w4.y, w4.z, w4.w};
#pragma unroll
      for (int ii = 0; ii < 4; ++ii)
#pragma unroll
        for (int jj = 0; jj < 4; ++jj)
          acc[ii][jj] = fmaf(a[ii], w[jj], acc[ii][jj]);
    }
    __syncthreads();
  }
#pragma unroll
  for (int ii = 0; ii < 4; ++ii) {
    int r = row0 + ty * 4 + ii;
#pragma unroll
    for (int jj = 0; jj < 4; ++jj) {
      int c = col0 + tx * 4 + jj;
      if (c < M) {
        float v = acc[ii][jj];
        if (bias) v += bias[c];
        if (do_relu) v = fmaxf(v, 0.f);
        C[(size_t)r * M + c] = v;
      }
    }
  }
}

// ---------------- attention: one q-row per thread, K/V tiles in LDS ----------------
// grid: x = bc*2 (qb + local batch), y = H_. qkv/o/wseq pointers pre-offset to chunk.
#define ATM 256
__global__ __launch_bounds__(256) void attn_kernel(
    const float* __restrict__ qkv, const int* __restrict__ wseq, float* __restrict__ o) {
  __shared__ float Ks[ATM][DK_ + 3];   // stride 28 floats = 112B (16B-aligned rows)
  __shared__ float Vs[ATM][DV_ + 3];
  __shared__ float maskadd[ATM];
  int qb = blockIdx.x & 1;
  int b  = blockIdx.x >> 1;            // batch local to this chunk
  int h  = blockIdx.y;
  int tid = threadIdx.x;
  int l = qb * ATM + tid;
  const float* base = qkv + (size_t)b * L_ * QKVD;
  float q[DK_];
  {
    const float* qr = base + (size_t)l * QKVD + h * DK_;
#pragma unroll
    for (int kk = 0; kk < DK_; ++kk) q[kk] = qr[kk];
  }
  const float inv_temper = 0.07071067811865475f;  // 1/sqrt(200)
  float mrun = -3.0e38f, ssum = 0.f;
  float acc[DV_] = {};
  for (int t0 = 0; t0 < L_; t0 += ATM) {
    for (int i = tid; i < ATM * DK_; i += 256) {
      int m = i / DK_, kk = i - m * DK_;
      Ks[m][kk] = base[(size_t)(t0 + m) * QKVD + 200 + h * DK_ + kk];
      Vs[m][kk] = base[(size_t)(t0 + m) * QKVD + 400 + h * DV_ + kk];
    }
    maskadd[tid] = (wseq[b * L_ + t0 + tid] == 0) ? -1e30f : 0.f;
    __syncthreads();
    for (int m = 0; m < ATM; ++m) {
      float d = 0.f;
#pragma unroll
      for (int kk = 0; kk < DK_; ++kk) d = fmaf(q[kk], Ks[m][kk], d);
      float s = d * inv_temper + maskadd[m];
      if (s > mrun) {                 // rare after warm-up: deferred rescale
        float r = __expf(mrun - s);
        ssum *= r;
#pragma unroll
        for (int kk = 0; kk < DV_; ++kk) acc[kk] *= r;
        mrun = s;
      }
      float p = __expf(s - mrun);
      ssum += p;
#pragma unroll
      for (int kk = 0; kk < DV_; ++kk) acc[kk] = fmaf(p, Vs[m][kk], acc[kk]);
    }
    __syncthreads();
  }
  float inv = 1.f / ssum;
  float* orow = o + (size_t)(b * L_ + l) * DM_ + h * DV_;
#pragma unroll
  for (int kk = 0; kk < DV_; ++kk) orow[kk] = acc[kk] * inv;
}

// ---------------- x_out = LayerNorm(y + x_in) (unbiased var, eps added to sigma) -------
__global__ __launch_bounds__(256) void add_ln_kernel(
    const float* __restrict__ y, const float* __restrict__ xin,
    const float* __restrict__ a, const float* __restrict__ bpar,
    float* __restrict__ xout) {
  int t = blockIdx.x * 4 + (threadIdx.x >> 6);
  int lane = threadIdx.x & 63;
  const float* yr = y + (size_t)t * DM_;
  const float* xr = xin + (size_t)t * DM_;
  float z0 = yr[lane] + xr[lane];
  float z1 = yr[lane + 64] + xr[lane + 64];
  float z2 = yr[lane + 128] + xr[lane + 128];
  float z3 = (lane < 8) ? (yr[lane + 192] + xr[lane + 192]) : 0.f;
  float sum = wave_sum(z0 + z1 + z2 + z3);
  float mu = sum * (1.f / DM_);
  float d0 = z0 - mu, d1 = z1 - mu, d2 = z2 - mu;
  float d3 = (lane < 8) ? (z3 - mu) : 0.f;
  float ss = wave_sum(d0 * d0 + d1 * d1 + d2 * d2 + d3 * d3);
  float inv = 1.f / (sqrtf(ss * (1.f / (DM_ - 1))) + 1e-3f);
  float* xo = xout + (size_t)t * DM_;
  xo[lane]       = d0 * inv * a[lane]       + bpar[lane];
  xo[lane + 64]  = d1 * inv * a[lane + 64]  + bpar[lane + 64];
  xo[lane + 128] = d2 * inv * a[lane + 128] + bpar[lane + 128];
  if (lane < 8)
    xo[lane + 192] = d3 * inv * a[lane + 192] + bpar[lane + 192];
}

extern "C" void kernel_launch(void* const* d_in, const int* in_sizes, int n_in,
                              void* d_out, int out_size, void* d_ws, size_t ws_size,
                              hipStream_t stream) {
  const float* we       = (const float*)d_in[0];
  const float* ee       = (const float*)d_in[1];
  const float* te       = (const float*)d_in[2];
  const float* pt       = (const float*)d_in[3];
  const float* bias     = (const float*)d_in[4];
  const float* w_qs     = (const float*)d_in[5];
  const float* w_ks     = (const float*)d_in[6];
  const float* w_vs     = (const float*)d_in[7];
  const float* w_o      = (const float*)d_in[8];
  const float* ffn_w1   = (const float*)d_in[9];
  const float* ffn_b1   = (const float*)d_in[10];
  const float* ffn_w2   = (const float*)d_in[11];
  const float* ffn_b2   = (const float*)d_in[12];
  const float* ln_ffn_a = (const float*)d_in[13];
  const float* ln_ffn_b = (const float*)d_in[14];
  const float* ln_attn_a= (const float*)d_in[15];
  const float* ln_attn_b= (const float*)d_in[16];
  const int* wseq       = (const int*)d_in[17];
  const int* eseq       = (const int*)d_in[18];
  const int* tseq       = (const int*)d_in[19];
  const int* pseq       = (const int*)d_in[20];
  float* out = (float*)d_out;

  // ---- workspace layout (floats), adaptive to ws_size ----
  // x: NTOK*DM | Wqkv: NL*QKVD*DM | scratch: (NTOK/NC)*800  (DFF == QKVD+DM == 800)
  // y lives in d_out (exactly NTOK*DM floats).
  const size_t fixed = (size_t)NTOK * DM_ + (size_t)NL_ * QKVD * DM_;
  size_t avail = ws_size / sizeof(float);
  int NC = 1;
  while (NC < 16 && fixed + (size_t)(NTOK / NC) * 800 > avail) NC <<= 1;
  if (fixed + (size_t)(NTOK / NC) * 800 > avail) return;  // ws hopelessly small

  const int chunkTok = NTOK / NC;       // multiple of 64 (>=1024)
  const int bc       = B_ / NC;         // batches per chunk (>=2)

  float* x       = (float*)d_ws;                       // NTOK*DM_
  float* Wqkv    = x + (size_t)NTOK * DM_;             // NL*QKVD*DM_
  float* scratch = Wqkv + (size_t)NL_ * QKVD * DM_;    // chunkTok*800
  float* y       = out;                                // aliases d_out
  float* h   = scratch;                                // chunkTok*DFF_
  float* qkv = scratch;                                // chunkTok*QKVD
  float* o   = scratch + (size_t)chunkTok * QKVD;      // chunkTok*DM_

  embed_kernel<<<NTOK / 4, 256, 0, stream>>>(we, ee, te, pt, bias, wseq, eseq, tseq, pseq, x);
  int rp = NL_ * QKVD * DM_;
  repack_qkv_kernel<<<(rp + 255) / 256, 256, 0, stream>>>(w_qs, w_ks, w_vs, Wqkv);

  dim3 gFFN1(chunkTok / GBM, (DFF_ + GBN - 1) / GBN);
  dim3 gDM(chunkTok / GBM, (DM_ + GBN - 1) / GBN);
  dim3 gQKV(chunkTok / GBM, (QKVD + GBN - 1) / GBN);
  dim3 gAttn(bc * 2, H_);

  for (int i = 0; i < NL_; ++i) {
    for (int c = 0; c < NC; ++c) {
      size_t t0 = (size_t)c * chunkTok;
      gemm_bias_kernel<<<gFFN1, 256, 0, stream>>>(x + t0 * DM_,
          ffn_w1 + (size_t)i * DFF_ * DM_, ffn_b1 + i * DFF_, h, DFF_, DM_, 1);
      gemm_bias_kernel<<<gDM, 256, 0, stream>>>(h,
          ffn_w2 + (size_t)i * DM_ * DFF_, ffn_b2 + i * DM_, y + t0 * DM_, DM_, DFF_, 0);
      add_ln_kernel<<<chunkTok / 4, 256, 0, stream>>>(y + t0 * DM_, x + t0 * DM_,
          ln_ffn_a + i * DM_, ln_ffn_b + i * DM_, x + t0 * DM_);
    }
    for (int c = 0; c < NC; ++c) {
      size_t t0 = (size_t)c * chunkTok;
      gemm_bias_kernel<<<gQKV, 256, 0, stream>>>(x + t0 * DM_,
          Wqkv + (size_t)i * QKVD * DM_, nullptr, qkv, QKVD, DM_, 0);
      attn_kernel<<<gAttn, 256, 0, stream>>>(qkv, wseq + t0, o);
      gemm_bias_kernel<<<gDM, 256, 0, stream>>>(o,
          w_o + (size_t)i * DM_ * (H_ * DV_), nullptr, y + t0 * DM_, DM_, DM_, 0);
      add_ln_kernel<<<chunkTok / 4, 256, 0, stream>>>(y + t0 * DM_, x + t0 * DM_,
          ln_attn_a + i * DM_, ln_attn_b + i * DM_,
          ((i == NL_ - 1) ? out : x) + t0 * DM_);
    }
  }
}

// Round 5
// 953.111 us; speedup vs baseline: 1.5092x; 1.5092x over previous
//
#include <hip/hip_runtime.h>
#include <math.h>

#define B_ 32
#define L_ 512
#define NTOK 16384      // B_*L_
#define NL_ 3
#define H_ 8
#define DK_ 25
#define DV_ 25
#define DM_ 200
#define DFF_ 800
#define QKVD 600        // H_*DK_*3
#define WD_ 150
#define TD_ 50
#define KP_ 224         // DM_ padded to multiple of 32

typedef unsigned short u16;
typedef short bf16x8 __attribute__((ext_vector_type(8)));   // bf16 bits in shorts (guide §3)
typedef float f32x4 __attribute__((ext_vector_type(4)));

__device__ __forceinline__ u16 f2bf(float v) {
  union { float f; unsigned u; } x; x.f = v;
  unsigned r = x.u + 0x7fffu + ((x.u >> 16) & 1u);
  return (u16)(r >> 16);
}

__device__ __forceinline__ float wave_sum(float v) {
#pragma unroll
  for (int off = 32; off > 0; off >>= 1) v += __shfl_xor(v, off, 64);
  return v;
}

// ---------------- embedding + bias + positional -> x fp32 and xb bf16[KP_] ----------------
__global__ __launch_bounds__(256) void embed_kernel(
    const float* __restrict__ we, const float* __restrict__ ee, const float* __restrict__ te,
    const float* __restrict__ pt, const float* __restrict__ bias,
    const int* __restrict__ wseq, const int* __restrict__ eseq, const int* __restrict__ tseq,
    const int* __restrict__ pseq, float* __restrict__ x, u16* __restrict__ xb) {
  int t = blockIdx.x * 4 + (threadIdx.x >> 6);
  int lane = threadIdx.x & 63;
  const float* wr = we + (size_t)wseq[t] * WD_;
  const float* er = ee + (size_t)eseq[t] * WD_;
  const float* tr = te + (size_t)tseq[t] * TD_;
  const float* pr = pt + (size_t)pseq[t] * DM_;
  float* xr = x + (size_t)t * DM_;
  u16* xbr = xb + (size_t)t * KP_;
#pragma unroll
  for (int d0 = 0; d0 < 256; d0 += 64) {
    int d = d0 + lane;
    if (d < DM_) {
      float v = (d < WD_) ? (wr[d] + er[d]) : tr[d - WD_];
      v = v + bias[d] + pr[d];
      xr[d] = v;
      xbr[d] = f2bf(v);
    } else if (d < KP_) {
      xbr[d] = 0;
    }
  }
}

// ---------------- generic fp32 [rows][kin] -> bf16 [rows][kout] (zero-pad) ----------------
__global__ __launch_bounds__(256) void castpad_kernel(
    const float* __restrict__ src, u16* __restrict__ dst, int rows, int kin, int kout) {
  int idx = blockIdx.x * 256 + threadIdx.x;
  if (idx >= rows * kout) return;
  int r = idx / kout, c = idx - r * kout;
  dst[idx] = (c < kin) ? f2bf(src[(size_t)r * kin + c]) : (u16)0;
}

// ---------------- pack+cast w_qs/w_ks/w_vs -> bf16 [NL][600][KP_] ----------------
__global__ __launch_bounds__(256) void repack_qkv_kernel(
    const float* __restrict__ wq, const float* __restrict__ wk, const float* __restrict__ wv,
    u16* __restrict__ Wp) {
  int idx = blockIdx.x * 256 + threadIdx.x;
  if (idx >= NL_ * QKVD * KP_) return;
  int d = idx % KP_;
  int c = (idx / KP_) % QKVD;
  int i = idx / (KP_ * QKVD);
  if (d >= DM_) { Wp[idx] = 0; return; }
  const float* src = wq; int cc = c;
  if (c >= 400)      { src = wv; cc = c - 400; }
  else if (c >= 200) { src = wk; cc = c - 200; }
  int h = cc / DK_, kk = cc % DK_;
  Wp[idx] = f2bf(src[(((size_t)i * H_ + h) * DM_ + d) * DK_ + kk]);
}

// ---------------- MFMA GEMM: C[rows][M] = A[rows][Ka](bf16) * W[M][Ka](bf16)^T ----------
// 128x128 block, 4 waves (2x2), each wave 64x64 (4x4 frags of 16x16x32).
// LDS row stride = 40 shorts (80B): lane-vs-lane word-bank pattern (20r mod 32) -> only
// 2-way aliasing within a 16-lane phase (free per m136).
#define LDS_LD 40
template<int BIAS, int RELU, int BF16OUT>
__global__ __launch_bounds__(256) void mfma_gemm(
    const u16* __restrict__ A, const u16* __restrict__ W,
    const float* __restrict__ bias, void* __restrict__ Cv, int M, int Ka) {
  __shared__ __align__(16) u16 As[128 * LDS_LD];
  __shared__ __align__(16) u16 Ws[128 * LDS_LD];
  int row0 = blockIdx.x * 128;
  int col0 = blockIdx.y * 128;
  int tid = threadIdx.x;
  int w = tid >> 6, l = tid & 63;
  int wr = w >> 1, wc = w & 1;

  // staging: 512 16B-chunks per 128x32 tile; thread handles chunks ch0, ch0+256
  int ch0 = w * 64 + l, ch1 = ch0 + 256;
  int r0 = ch0 >> 2, c0 = ch0 & 3;
  int r1 = ch1 >> 2, c1 = ch1 & 3;
  const u16* Ab0 = A + (size_t)(row0 + r0) * Ka + c0 * 8;
  const u16* Ab1 = A + (size_t)(row0 + r1) * Ka + c1 * 8;
  int wr0 = col0 + r0; if (wr0 >= M) wr0 = M - 1;   // clamp: garbage cols guarded at store
  int wr1 = col0 + r1; if (wr1 >= M) wr1 = M - 1;
  const u16* Wb0 = W + (size_t)wr0 * Ka + c0 * 8;
  const u16* Wb1 = W + (size_t)wr1 * Ka + c1 * 8;
  u16* dA0 = As + r0 * LDS_LD + c0 * 8;
  u16* dA1 = As + r1 * LDS_LD + c1 * 8;
  u16* dW0 = Ws + r0 * LDS_LD + c0 * 8;
  u16* dW1 = Ws + r1 * LDS_LD + c1 * 8;

  // fragment read offsets (shorts): A/B frag = lane(row)=l&15, k-chunk=(l>>4)*8
  int k8 = l >> 4, lr = l & 15;
  int a_off[4], w_off[4];
#pragma unroll
  for (int m = 0; m < 4; ++m) {
    a_off[m] = (wr * 64 + m * 16 + lr) * LDS_LD + k8 * 8;
    w_off[m] = (wc * 64 + m * 16 + lr) * LDS_LD + k8 * 8;
  }

  f32x4 acc[4][4];
#pragma unroll
  for (int m = 0; m < 4; ++m)
#pragma unroll
    for (int n = 0; n < 4; ++n) acc[m][n] = (f32x4){0.f, 0.f, 0.f, 0.f};

  int nk = Ka >> 5;
  for (int ks = 0; ks < nk; ++ks) {
    int k0 = ks * 32;
    uint4 va0 = *(const uint4*)(Ab0 + k0);
    uint4 va1 = *(const uint4*)(Ab1 + k0);
    uint4 vw0 = *(const uint4*)(Wb0 + k0);
    uint4 vw1 = *(const uint4*)(Wb1 + k0);
    __syncthreads();                       // prev iteration's frag reads done
    *(uint4*)dA0 = va0;
    *(uint4*)dA1 = va1;
    *(uint4*)dW0 = vw0;
    *(uint4*)dW1 = vw1;
    __syncthreads();                       // tile visible to all waves
    bf16x8 af[4], wf[4];
#pragma unroll
    for (int m = 0; m < 4; ++m) af[m] = *(const bf16x8*)(As + a_off[m]);
#pragma unroll
    for (int n = 0; n < 4; ++n) wf[n] = *(const bf16x8*)(Ws + w_off[n]);
#pragma unroll
    for (int m = 0; m < 4; ++m)
#pragma unroll
      for (int n = 0; n < 4; ++n)
        acc[m][n] = __builtin_amdgcn_mfma_f32_16x16x32_bf16(af[m], wf[n], acc[m][n], 0, 0, 0);
  }

  // epilogue: D frag mapping col=lane&15, row=(lane>>4)*4+reg  [m89]
#pragma unroll
  for (int n = 0; n < 4; ++n) {
    int col = col0 + wc * 64 + n * 16 + lr;
    if (col >= M) continue;
    float bb = BIAS ? bias[col] : 0.f;
#pragma unroll
    for (int m = 0; m < 4; ++m) {
      int rbase = row0 + wr * 64 + m * 16 + k8 * 4;
#pragma unroll
      for (int j = 0; j < 4; ++j) {
        float v = acc[m][n][j] + bb;
        if (RELU) v = fmaxf(v, 0.f);
        if (BF16OUT) ((u16*)Cv)[(size_t)(rbase + j) * M + col] = f2bf(v);
        else ((float*)Cv)[(size_t)(rbase + j) * M + col] = v;
      }
    }
  }
}

// ---------------- attention: one q-row/thread, ILP-optimized, bf16-padded output -------
#define ATM 256
__global__ __launch_bounds__(256) void attn_kernel(
    const float* __restrict__ qkv, const int* __restrict__ wseq, u16* __restrict__ ob) {
  __shared__ float Ks[ATM][DK_ + 3];
  __shared__ float Vs[ATM][DV_ + 3];
  __shared__ float maskadd[ATM];
  int qb = blockIdx.x & 1;
  int b  = blockIdx.x >> 1;            // batch local to chunk
  int h  = blockIdx.y;
  int tid = threadIdx.x;
  int l = qb * ATM + tid;
  const float* base = qkv + (size_t)b * L_ * QKVD;
  float q[DK_];
  {
    const float* qr = base + (size_t)l * QKVD + h * DK_;
#pragma unroll
    for (int kk = 0; kk < DK_; ++kk) q[kk] = qr[kk];
  }
  const float invt = 0.07071067811865475f;  // 1/sqrt(200)
  float mrun = -3.0e38f, ssum = 0.f;
  float acc[DV_] = {};
  for (int t0 = 0; t0 < L_; t0 += ATM) {
    for (int i = tid; i < ATM * DK_; i += 256) {
      int m = i / DK_, kk = i - m * DK_;
      Ks[m][kk] = base[(size_t)(t0 + m) * QKVD + 200 + h * DK_ + kk];
      Vs[m][kk] = base[(size_t)(t0 + m) * QKVD + 400 + h * DV_ + kk];
    }
    maskadd[tid] = (wseq[b * L_ + t0 + tid] == 0) ? -1e30f : 0.f;
    __syncthreads();
    for (int m = 0; m < ATM; m += 2) {
      const float* kra = Ks[m];
      const float* krb = Ks[m + 1];
      float da0 = 0.f, da1 = 0.f, da2 = 0.f, da3 = 0.f;
      float db0 = 0.f, db1 = 0.f, db2 = 0.f, db3 = 0.f;
#pragma unroll
      for (int kk = 0; kk < 24; kk += 4) {
        da0 = fmaf(q[kk + 0], kra[kk + 0], da0);
        da1 = fmaf(q[kk + 1], kra[kk + 1], da1);
        da2 = fmaf(q[kk + 2], kra[kk + 2], da2);
        da3 = fmaf(q[kk + 3], kra[kk + 3], da3);
        db0 = fmaf(q[kk + 0], krb[kk + 0], db0);
        db1 = fmaf(q[kk + 1], krb[kk + 1], db1);
        db2 = fmaf(q[kk + 2], krb[kk + 2], db2);
        db3 = fmaf(q[kk + 3], krb[kk + 3], db3);
      }
      da0 = fmaf(q[24], kra[24], da0);
      db0 = fmaf(q[24], krb[24], db0);
      float sa = fmaf((da0 + da1) + (da2 + da3), invt, maskadd[m]);
      float sb = fmaf((db0 + db1) + (db2 + db3), invt, maskadd[m + 1]);
      float mx = fmaxf(sa, sb);
      if (mx > mrun) {                 // deferred rescale (rare after warm-up)
        float r = __expf(mrun - mx);
        ssum *= r;
#pragma unroll
        for (int kk = 0; kk < DV_; ++kk) acc[kk] *= r;
        mrun = mx;
      }
      float pa = __expf(sa - mrun);
      float pb = __expf(sb - mrun);
      ssum += pa + pb;
      const float* vra = Vs[m];
      const float* vrb = Vs[m + 1];
#pragma unroll
      for (int kk = 0; kk < DV_; ++kk)
        acc[kk] = fmaf(pb, vrb[kk], fmaf(pa, vra[kk], acc[kk]));
    }
    __syncthreads();
  }
  float inv = 1.f / ssum;
  u16* orow = ob + (size_t)(b * L_ + l) * KP_ + h * DV_;
#pragma unroll
  for (int kk = 0; kk < DV_; ++kk) orow[kk] = f2bf(acc[kk] * inv);
  if (h == H_ - 1) {                    // zero the K-pad columns 200..223
    u16* prow = ob + (size_t)(b * L_ + l) * KP_ + DM_;
#pragma unroll
    for (int kk = 0; kk < KP_ - DM_; ++kk) prow[kk] = 0;
  }
}

// ------- x_out = LayerNorm(y + x_in) (unbiased var, eps on sigma); also writes bf16 xb ----
__global__ __launch_bounds__(256) void add_ln_kernel(
    const float* __restrict__ y, const float* __restrict__ xin,
    const float* __restrict__ a, const float* __restrict__ bpar,
    float* __restrict__ xout, u16* __restrict__ xb) {
  int t = blockIdx.x * 4 + (threadIdx.x >> 6);
  int lane = threadIdx.x & 63;
  const float* yr = y + (size_t)t * DM_;
  const float* xr = xin + (size_t)t * DM_;
  float z0 = yr[lane] + xr[lane];
  float z1 = yr[lane + 64] + xr[lane + 64];
  float z2 = yr[lane + 128] + xr[lane + 128];
  float z3 = (lane < 8) ? (yr[lane + 192] + xr[lane + 192]) : 0.f;
  float sum = wave_sum(z0 + z1 + z2 + z3);
  float mu = sum * (1.f / DM_);
  float d0 = z0 - mu, d1 = z1 - mu, d2 = z2 - mu;
  float d3 = (lane < 8) ? (z3 - mu) : 0.f;
  float ss = wave_sum(d0 * d0 + d1 * d1 + d2 * d2 + d3 * d3);
  float inv = 1.f / (sqrtf(ss * (1.f / (DM_ - 1))) + 1e-3f);
  float* xo = xout + (size_t)t * DM_;
  u16* xbr = xb + (size_t)t * KP_;
  float o0 = d0 * inv * a[lane] + bpar[lane];
  float o1 = d1 * inv * a[lane + 64] + bpar[lane + 64];
  float o2 = d2 * inv * a[lane + 128] + bpar[lane + 128];
  xo[lane] = o0;        xbr[lane] = f2bf(o0);
  xo[lane + 64] = o1;   xbr[lane + 64] = f2bf(o1);
  xo[lane + 128] = o2;  xbr[lane + 128] = f2bf(o2);
  if (lane < 8) {
    float o3 = d3 * inv * a[lane + 192] + bpar[lane + 192];
    xo[lane + 192] = o3;
    xbr[lane + 192] = f2bf(o3);
  } else if (lane < 32) {
    xbr[lane + 192] = 0;  // pad cols 200..223
  }
}

extern "C" void kernel_launch(void* const* d_in, const int* in_sizes, int n_in,
                              void* d_out, int out_size, void* d_ws, size_t ws_size,
                              hipStream_t stream) {
  const float* we       = (const float*)d_in[0];
  const float* ee       = (const float*)d_in[1];
  const float* te       = (const float*)d_in[2];
  const float* pt       = (const float*)d_in[3];
  const float* bias     = (const float*)d_in[4];
  const float* w_qs     = (const float*)d_in[5];
  const float* w_ks     = (const float*)d_in[6];
  const float* w_vs     = (const float*)d_in[7];
  const float* w_o      = (const float*)d_in[8];
  const float* ffn_w1   = (const float*)d_in[9];
  const float* ffn_b1   = (const float*)d_in[10];
  const float* ffn_w2   = (const float*)d_in[11];
  const float* ffn_b2   = (const float*)d_in[12];
  const float* ln_ffn_a = (const float*)d_in[13];
  const float* ln_ffn_b = (const float*)d_in[14];
  const float* ln_attn_a= (const float*)d_in[15];
  const float* ln_attn_b= (const float*)d_in[16];
  const int* wseq       = (const int*)d_in[17];
  const int* eseq       = (const int*)d_in[18];
  const int* tseq       = (const int*)d_in[19];
  const int* pseq       = (const int*)d_in[20];
  float* out = (float*)d_out;

  // ---- workspace layout (bytes), adaptive chunking ----
  char* p = (char*)d_ws;
  float* x  = (float*)p; p += (size_t)NTOK * DM_ * 4;           // 13,107,200
  u16* xb   = (u16*)p;   p += (size_t)NTOK * KP_ * 2;           //  7,340,032
  u16* W1b  = (u16*)p;   p += (size_t)NL_ * DFF_ * KP_ * 2;     //  1,075,200
  u16* W2b  = (u16*)p;   p += (size_t)NL_ * DM_ * DFF_ * 2;     //    960,000
  u16* Wqb  = (u16*)p;   p += (size_t)NL_ * QKVD * KP_ * 2;     //    806,400
  u16* Wob  = (u16*)p;   p += (size_t)NL_ * DM_ * KP_ * 2;      //    268,800
  char* S   = p;                                                // chunk scratch
  size_t fixedB = (size_t)(S - (char*)d_ws);
  // per-token scratch: max(hb 1600B, qkv 2400B + ob 448B) = 2848B
  int NC = 1;
  while (NC < 16 && fixedB + (size_t)(NTOK / NC) * 2848 > ws_size) NC <<= 1;
  if (fixedB + (size_t)(NTOK / NC) * 2848 > ws_size) return;  // ws hopelessly small
  const int chunkTok = NTOK / NC;       // multiple of 1024
  const int bc       = B_ / NC;         // batches per chunk (>=2)

  u16* hb     = (u16*)S;                         // [chunkTok][800] bf16
  float* qkv  = (float*)S;                       // [chunkTok][600] fp32
  u16* ob     = (u16*)(S + (size_t)chunkTok * QKVD * 4);  // [chunkTok][KP_] bf16
  float* y    = out;                             // [NTOK][200] fp32, aliases d_out

  embed_kernel<<<NTOK / 4, 256, 0, stream>>>(we, ee, te, pt, bias, wseq, eseq, tseq, pseq,
                                             x, xb);
  {
    int n1 = NL_ * DFF_ * KP_;
    castpad_kernel<<<(n1 + 255) / 256, 256, 0, stream>>>(ffn_w1, W1b, NL_ * DFF_, DM_, KP_);
    int n2 = NL_ * DM_ * DFF_;
    castpad_kernel<<<(n2 + 255) / 256, 256, 0, stream>>>(ffn_w2, W2b, NL_ * DM_, DFF_, DFF_);
    int n3 = NL_ * QKVD * KP_;
    repack_qkv_kernel<<<(n3 + 255) / 256, 256, 0, stream>>>(w_qs, w_ks, w_vs, Wqb);
    int n4 = NL_ * DM_ * KP_;
    castpad_kernel<<<(n4 + 255) / 256, 256, 0, stream>>>(w_o, Wob, NL_ * DM_, DM_, KP_);
  }

  dim3 gF1(chunkTok / 128, (DFF_ + 127) / 128);   // x7
  dim3 gF2(chunkTok / 128, (DM_ + 127) / 128);    // x2
  dim3 gQK(chunkTok / 128, (QKVD + 127) / 128);   // x5
  dim3 gAttn(bc * 2, H_);

  for (int i = 0; i < NL_; ++i) {
    for (int c = 0; c < NC; ++c) {
      size_t t0 = (size_t)c * chunkTok;
      mfma_gemm<1, 1, 1><<<gF1, 256, 0, stream>>>(xb + t0 * KP_,
          W1b + (size_t)i * DFF_ * KP_, ffn_b1 + i * DFF_, hb, DFF_, KP_);
      mfma_gemm<1, 0, 0><<<gF2, 256, 0, stream>>>(hb,
          W2b + (size_t)i * DM_ * DFF_, ffn_b2 + i * DM_, y + t0 * DM_, DM_, DFF_);
      add_ln_kernel<<<chunkTok / 4, 256, 0, stream>>>(y + t0 * DM_, x + t0 * DM_,
          ln_ffn_a + i * DM_, ln_ffn_b + i * DM_, x + t0 * DM_, xb + t0 * KP_);
    }
    for (int c = 0; c < NC; ++c) {
      size_t t0 = (size_t)c * chunkTok;
      mfma_gemm<0, 0, 0><<<gQK, 256, 0, stream>>>(xb + t0 * KP_,
          Wqb + (size_t)i * QKVD * KP_, nullptr, qkv, QKVD, KP_);
      attn_kernel<<<gAttn, 256, 0, stream>>>(qkv, wseq + t0, ob);
      mfma_gemm<0, 0, 0><<<gF2, 256, 0, stream>>>(ob,
          Wob + (size_t)i * DM_ * KP_, nullptr, y + t0 * DM_, DM_, KP_);
      add_ln_kernel<<<chunkTok / 4, 256, 0, stream>>>(y + t0 * DM_, x + t0 * DM_,
          ln_attn_a + i * DM_, ln_attn_b + i * DM_,
          ((i == NL_ - 1) ? out : x) + t0 * DM_, xb + t0 * KP_);
    }
  }
}

// Round 8
// 762.151 us; speedup vs baseline: 1.8874x; 1.2506x over previous
//
#include <hip/hip_runtime.h>
#include <math.h>

#define B_ 32
#define L_ 512
#define NTOK 16384      // B_*L_
#define NL_ 3
#define H_ 8
#define DK_ 25
#define DV_ 25
#define DM_ 200
#define DFF_ 800
#define QKVD 600        // H_*DK_*3
#define WD_ 150
#define TD_ 50
#define KP_ 224         // DM_ padded to multiple of 32

typedef unsigned short u16;
typedef short bf16x8 __attribute__((ext_vector_type(8)));   // bf16 bits in shorts (guide §3)
typedef float f32x4 __attribute__((ext_vector_type(4)));

__device__ __forceinline__ u16 f2bf(float v) {
  union { float f; unsigned u; } x; x.f = v;
  unsigned r = x.u + 0x7fffu + ((x.u >> 16) & 1u);
  return (u16)(r >> 16);
}

__device__ __forceinline__ float wave_sum(float v) {
#pragma unroll
  for (int off = 32; off > 0; off >>= 1) v += __shfl_xor(v, off, 64);
  return v;
}

// ---------------- embedding + bias + positional -> x fp32 and xb bf16[KP_] ----------------
__global__ __launch_bounds__(256) void embed_kernel(
    const float* __restrict__ we, const float* __restrict__ ee, const float* __restrict__ te,
    const float* __restrict__ pt, const float* __restrict__ bias,
    const int* __restrict__ wseq, const int* __restrict__ eseq, const int* __restrict__ tseq,
    const int* __restrict__ pseq, float* __restrict__ x, u16* __restrict__ xb) {
  int t = blockIdx.x * 4 + (threadIdx.x >> 6);
  int lane = threadIdx.x & 63;
  const float* wr = we + (size_t)wseq[t] * WD_;
  const float* er = ee + (size_t)eseq[t] * WD_;
  const float* tr = te + (size_t)tseq[t] * TD_;
  const float* pr = pt + (size_t)pseq[t] * DM_;
  float* xr = x + (size_t)t * DM_;
  u16* xbr = xb + (size_t)t * KP_;
#pragma unroll
  for (int d0 = 0; d0 < 256; d0 += 64) {
    int d = d0 + lane;
    if (d < DM_) {
      float v = (d < WD_) ? (wr[d] + er[d]) : tr[d - WD_];
      v = v + bias[d] + pr[d];
      xr[d] = v;
      xbr[d] = f2bf(v);
    } else if (d < KP_) {
      xbr[d] = 0;
    }
  }
}

// ---------------- generic fp32 [rows][kin] -> bf16 [rows][kout] (zero-pad) ----------------
__global__ __launch_bounds__(256) void castpad_kernel(
    const float* __restrict__ src, u16* __restrict__ dst, int rows, int kin, int kout) {
  int idx = blockIdx.x * 256 + threadIdx.x;
  if (idx >= rows * kout) return;
  int r = idx / kout, c = idx - r * kout;
  dst[idx] = (c < kin) ? f2bf(src[(size_t)r * kin + c]) : (u16)0;
}

// ---------------- pack+cast w_qs/w_ks/w_vs -> bf16 [NL][600][KP_] ----------------
__global__ __launch_bounds__(256) void repack_qkv_kernel(
    const float* __restrict__ wq, const float* __restrict__ wk, const float* __restrict__ wv,
    u16* __restrict__ Wp) {
  int idx = blockIdx.x * 256 + threadIdx.x;
  if (idx >= NL_ * QKVD * KP_) return;
  int d = idx % KP_;
  int c = (idx / KP_) % QKVD;
  int i = idx / (KP_ * QKVD);
  if (d >= DM_) { Wp[idx] = 0; return; }
  const float* src = wq; int cc = c;
  if (c >= 400)      { src = wv; cc = c - 400; }
  else if (c >= 200) { src = wk; cc = c - 200; }
  int h = cc / DK_, kk = cc % DK_;
  Wp[idx] = f2bf(src[(((size_t)i * H_ + h) * DM_ + d) * DK_ + kk]);
}

// ---------------- MFMA GEMM: C[rows][M] = A[rows][Ka](bf16) * W[M][Ka](bf16)^T ----------
#define LDS_LD 40
template<int BIAS, int RELU, int BF16OUT>
__global__ __launch_bounds__(256) void mfma_gemm(
    const u16* __restrict__ A, const u16* __restrict__ W,
    const float* __restrict__ bias, void* __restrict__ Cv, int M, int Ka) {
  __shared__ __align__(16) u16 As[128 * LDS_LD];
  __shared__ __align__(16) u16 Ws[128 * LDS_LD];
  int row0 = blockIdx.x * 128;
  int col0 = blockIdx.y * 128;
  int tid = threadIdx.x;
  int w = tid >> 6, l = tid & 63;
  int wr = w >> 1, wc = w & 1;

  int ch0 = w * 64 + l, ch1 = ch0 + 256;
  int r0 = ch0 >> 2, c0 = ch0 & 3;
  int r1 = ch1 >> 2, c1 = ch1 & 3;
  const u16* Ab0 = A + (size_t)(row0 + r0) * Ka + c0 * 8;
  const u16* Ab1 = A + (size_t)(row0 + r1) * Ka + c1 * 8;
  int wr0 = col0 + r0; if (wr0 >= M) wr0 = M - 1;
  int wr1 = col0 + r1; if (wr1 >= M) wr1 = M - 1;
  const u16* Wb0 = W + (size_t)wr0 * Ka + c0 * 8;
  const u16* Wb1 = W + (size_t)wr1 * Ka + c1 * 8;
  u16* dA0 = As + r0 * LDS_LD + c0 * 8;
  u16* dA1 = As + r1 * LDS_LD + c1 * 8;
  u16* dW0 = Ws + r0 * LDS_LD + c0 * 8;
  u16* dW1 = Ws + r1 * LDS_LD + c1 * 8;

  int k8 = l >> 4, lr = l & 15;
  int a_off[4], w_off[4];
#pragma unroll
  for (int m = 0; m < 4; ++m) {
    a_off[m] = (wr * 64 + m * 16 + lr) * LDS_LD + k8 * 8;
    w_off[m] = (wc * 64 + m * 16 + lr) * LDS_LD + k8 * 8;
  }

  f32x4 acc[4][4];
#pragma unroll
  for (int m = 0; m < 4; ++m)
#pragma unroll
    for (int n = 0; n < 4; ++n) acc[m][n] = (f32x4){0.f, 0.f, 0.f, 0.f};

  int nk = Ka >> 5;
  for (int ks = 0; ks < nk; ++ks) {
    int k0 = ks * 32;
    uint4 va0 = *(const uint4*)(Ab0 + k0);
    uint4 va1 = *(const uint4*)(Ab1 + k0);
    uint4 vw0 = *(const uint4*)(Wb0 + k0);
    uint4 vw1 = *(const uint4*)(Wb1 + k0);
    __syncthreads();
    *(uint4*)dA0 = va0;
    *(uint4*)dA1 = va1;
    *(uint4*)dW0 = vw0;
    *(uint4*)dW1 = vw1;
    __syncthreads();
    bf16x8 af[4], wf[4];
#pragma unroll
    for (int m = 0; m < 4; ++m) af[m] = *(const bf16x8*)(As + a_off[m]);
#pragma unroll
    for (int n = 0; n < 4; ++n) wf[n] = *(const bf16x8*)(Ws + w_off[n]);
#pragma unroll
    for (int m = 0; m < 4; ++m)
#pragma unroll
      for (int n = 0; n < 4; ++n)
        acc[m][n] = __builtin_amdgcn_mfma_f32_16x16x32_bf16(af[m], wf[n], acc[m][n], 0, 0, 0);
  }

#pragma unroll
  for (int n = 0; n < 4; ++n) {
    int col = col0 + wc * 64 + n * 16 + lr;
    if (col >= M) continue;
    float bb = BIAS ? bias[col] : 0.f;
#pragma unroll
    for (int m = 0; m < 4; ++m) {
      int rbase = row0 + wr * 64 + m * 16 + k8 * 4;
#pragma unroll
      for (int j = 0; j < 4; ++j) {
        float v = acc[m][n][j] + bb;
        if (RELU) v = fmaxf(v, 0.f);
        if (BF16OUT) ((u16*)Cv)[(size_t)(rbase + j) * M + col] = f2bf(v);
        else ((float*)Cv)[(size_t)(rbase + j) * M + col] = v;
      }
    }
  }
}

// ---------------- fused flash MFMA attention ----------------
// block = (qtile 32 rows, h, b); 4 waves: wave w -> S/O quadrant (qh=w>>1, kh=vh=w&1).
// Frag layouts identical to mfma_gemm (HW-validated round 5).
__global__ __launch_bounds__(256) void attn_mfma_kernel(
    const float* __restrict__ qkv, const int* __restrict__ wseq, u16* __restrict__ ob) {
  __shared__ __align__(16) u16 Qs[32 * 40];
  __shared__ __align__(16) u16 Ks[32 * 40];
  __shared__ __align__(16) u16 VTs[32 * 40];
  __shared__ __align__(16) u16 Ps[32 * 40];
  __shared__ float S32[32 * 36];
  __shared__ float maskadd[512];
  __shared__ float mrun[32], ssum[32], rbuf[32];

  int qt = blockIdx.x, h = blockIdx.y, b = blockIdx.z;
  int tid = threadIdx.x;
  int w = tid >> 6, l = tid & 63;
  int qh = w >> 1, kh = w & 1;         // kh doubles as v-half for PV
  int lr = l & 15, k8 = l >> 4;

  const float* base = qkv + (size_t)b * L_ * QKVD;

  // stage maskadd[512] + Q tile [32][40] (bf16, zero-pad d>=25) + init stats
  maskadd[tid]       = (wseq[b * L_ + tid] == 0)       ? -1e30f : 0.f;
  maskadd[tid + 256] = (wseq[b * L_ + tid + 256] == 0) ? -1e30f : 0.f;
#pragma unroll
  for (int s = 0; s < 4; ++s) {
    int slot = tid * 4 + s;            // 0..1023
    int r = slot >> 5, d = slot & 31;
    float v = (d < DK_) ? base[(size_t)(qt * 32 + r) * QKVD + h * DK_ + d] : 0.f;
    Qs[r * 40 + d] = f2bf(v);
  }
  if (tid < 32) { mrun[tid] = -3.0e38f; ssum[tid] = 0.f; }
  __syncthreads();

  bf16x8 qf = *(const bf16x8*)(Qs + (qh * 16 + lr) * 40 + k8 * 8);  // Q frag in regs
  f32x4 oacc = (f32x4){0.f, 0.f, 0.f, 0.f};
  const float invt = 0.07071067811865475f;  // 1/sqrt(200)

  for (int kt = 0; kt < 16; ++kt) {
    // stage K-tile [key][dim] and VT-tile [v][key] (both bf16, zero-padded)
#pragma unroll
    for (int s = 0; s < 4; ++s) {
      int slot = tid * 4 + s;
      int r = slot >> 5, c = slot & 31;
      float kv = (c < DK_) ? base[(size_t)(kt * 32 + r) * QKVD + 200 + h * DK_ + c] : 0.f;
      Ks[r * 40 + c] = f2bf(kv);
      float vv = (r < DV_) ? base[(size_t)(kt * 32 + c) * QKVD + 400 + h * DV_ + r] : 0.f;
      VTs[r * 40 + c] = f2bf(vv);
    }
    __syncthreads();

    // QK^T quadrant -> S32 with scale+mask (D: col=l&15, row=4*k8+j)
    {
      bf16x8 kf = *(const bf16x8*)(Ks + (kh * 16 + lr) * 40 + k8 * 8);
      f32x4 sf = (f32x4){0.f, 0.f, 0.f, 0.f};
      sf = __builtin_amdgcn_mfma_f32_16x16x32_bf16(qf, kf, sf, 0, 0, 0);
      int colg = kh * 16 + lr;
      float ma = maskadd[kt * 32 + colg];
#pragma unroll
      for (int j = 0; j < 4; ++j) {
        int row = qh * 16 + k8 * 4 + j;
        S32[row * 36 + colg] = sf[j] * invt + ma;
      }
    }
    __syncthreads();

    // online softmax: thread -> row=tid>>3 (wave-local), seg=tid&7, cols seg*4..+3
    {
      int row = tid >> 3, seg = tid & 7;
      const float* srow = S32 + row * 36 + seg * 4;
      float s0 = srow[0], s1 = srow[1], s2 = srow[2], s3 = srow[3];
      float lm = fmaxf(fmaxf(s0, s1), fmaxf(s2, s3));
      lm = fmaxf(lm, __shfl_xor(lm, 1, 64));
      lm = fmaxf(lm, __shfl_xor(lm, 2, 64));
      lm = fmaxf(lm, __shfl_xor(lm, 4, 64));
      float om = mrun[row];
      float nm = fmaxf(om, lm);
      float r = __expf(om - nm);
      float p0 = __expf(s0 - nm), p1 = __expf(s1 - nm);
      float p2 = __expf(s2 - nm), p3 = __expf(s3 - nm);
      float ls = (p0 + p1) + (p2 + p3);
      ls += __shfl_xor(ls, 1, 64);
      ls += __shfl_xor(ls, 2, 64);
      ls += __shfl_xor(ls, 4, 64);
      if (seg == 0) { mrun[row] = nm; ssum[row] = ssum[row] * r + ls; rbuf[row] = r; }
      u16* pr = Ps + row * 40 + seg * 4;
      pr[0] = f2bf(p0); pr[1] = f2bf(p1); pr[2] = f2bf(p2); pr[3] = f2bf(p3);
    }
    __syncthreads();

    // rescale O-acc and PV mfma: O[q][v] += P[q][key] * VT[v][key]
    {
#pragma unroll
      for (int j = 0; j < 4; ++j) oacc[j] *= rbuf[qh * 16 + k8 * 4 + j];
      bf16x8 pf = *(const bf16x8*)(Ps + (qh * 16 + lr) * 40 + k8 * 8);
      bf16x8 vf = *(const bf16x8*)(VTs + (kh * 16 + lr) * 40 + k8 * 8);
      oacc = __builtin_amdgcn_mfma_f32_16x16x32_bf16(pf, vf, oacc, 0, 0, 0);
    }
    __syncthreads();   // protect Ks/VTs/Ps/stats before next staging
  }

  // write O (D: col v=kh*16+lr, rows qh*16+k8*4+j), scaled by 1/ssum
  {
    int v = kh * 16 + lr;
    if (v < DV_) {
#pragma unroll
      for (int j = 0; j < 4; ++j) {
        int row = qh * 16 + k8 * 4 + j;
        float inv = 1.f / ssum[row];
        int tok = qt * 32 + row;
        ob[(size_t)(b * L_ + tok) * KP_ + h * DV_ + v] = f2bf(oacc[j] * inv);
      }
    }
  }
  if (h == H_ - 1) {                    // zero K-pad cols 200..223 for this q-tile
    for (int idx = tid; idx < 32 * (KP_ - DM_); idx += 256) {
      int row = idx / (KP_ - DM_), c = idx % (KP_ - DM_);
      ob[(size_t)(b * L_ + qt * 32 + row) * KP_ + DM_ + c] = 0;
    }
  }
}

// ------- x_out = LayerNorm(y + x_in) (unbiased var, eps on sigma); also writes bf16 xb ----
__global__ __launch_bounds__(256) void add_ln_kernel(
    const float* __restrict__ y, const float* __restrict__ xin,
    const float* __restrict__ a, const float* __restrict__ bpar,
    float* __restrict__ xout, u16* __restrict__ xb) {
  int t = blockIdx.x * 4 + (threadIdx.x >> 6);
  int lane = threadIdx.x & 63;
  const float* yr = y + (size_t)t * DM_;
  const float* xr = xin + (size_t)t * DM_;
  float z0 = yr[lane] + xr[lane];
  float z1 = yr[lane + 64] + xr[lane + 64];
  float z2 = yr[lane + 128] + xr[lane + 128];
  float z3 = (lane < 8) ? (yr[lane + 192] + xr[lane + 192]) : 0.f;
  float sum = wave_sum(z0 + z1 + z2 + z3);
  float mu = sum * (1.f / DM_);
  float d0 = z0 - mu, d1 = z1 - mu, d2 = z2 - mu;
  float d3 = (lane < 8) ? (z3 - mu) : 0.f;
  float ss = wave_sum(d0 * d0 + d1 * d1 + d2 * d2 + d3 * d3);
  float inv = 1.f / (sqrtf(ss * (1.f / (DM_ - 1))) + 1e-3f);
  float* xo = xout + (size_t)t * DM_;
  u16* xbr = xb + (size_t)t * KP_;
  float o0 = d0 * inv * a[lane] + bpar[lane];
  float o1 = d1 * inv * a[lane + 64] + bpar[lane + 64];
  float o2 = d2 * inv * a[lane + 128] + bpar[lane + 128];
  xo[lane] = o0;        xbr[lane] = f2bf(o0);
  xo[lane + 64] = o1;   xbr[lane + 64] = f2bf(o1);
  xo[lane + 128] = o2;  xbr[lane + 128] = f2bf(o2);
  if (lane < 8) {
    float o3 = d3 * inv * a[lane + 192] + bpar[lane + 192];
    xo[lane + 192] = o3;
    xbr[lane + 192] = f2bf(o3);
  } else if (lane < 32) {
    xbr[lane + 192] = 0;  // pad cols 200..223
  }
}

extern "C" void kernel_launch(void* const* d_in, const int* in_sizes, int n_in,
                              void* d_out, int out_size, void* d_ws, size_t ws_size,
                              hipStream_t stream) {
  const float* we       = (const float*)d_in[0];
  const float* ee       = (const float*)d_in[1];
  const float* te       = (const float*)d_in[2];
  const float* pt       = (const float*)d_in[3];
  const float* bias     = (const float*)d_in[4];
  const float* w_qs     = (const float*)d_in[5];
  const float* w_ks     = (const float*)d_in[6];
  const float* w_vs     = (const float*)d_in[7];
  const float* w_o      = (const float*)d_in[8];
  const float* ffn_w1   = (const float*)d_in[9];
  const float* ffn_b1   = (const float*)d_in[10];
  const float* ffn_w2   = (const float*)d_in[11];
  const float* ffn_b2   = (const float*)d_in[12];
  const float* ln_ffn_a = (const float*)d_in[13];
  const float* ln_ffn_b = (const float*)d_in[14];
  const float* ln_attn_a= (const float*)d_in[15];
  const float* ln_attn_b= (const float*)d_in[16];
  const int* wseq       = (const int*)d_in[17];
  const int* eseq       = (const int*)d_in[18];
  const int* tseq       = (const int*)d_in[19];
  const int* pseq       = (const int*)d_in[20];
  float* out = (float*)d_out;

  // ---- workspace layout (bytes), adaptive chunking ----
  char* p = (char*)d_ws;
  float* x  = (float*)p; p += (size_t)NTOK * DM_ * 4;           // 13,107,200
  u16* xb   = (u16*)p;   p += (size_t)NTOK * KP_ * 2;           //  7,340,032
  u16* W1b  = (u16*)p;   p += (size_t)NL_ * DFF_ * KP_ * 2;     //  1,075,200
  u16* W2b  = (u16*)p;   p += (size_t)NL_ * DM_ * DFF_ * 2;     //    960,000
  u16* Wqb  = (u16*)p;   p += (size_t)NL_ * QKVD * KP_ * 2;     //    806,400
  u16* Wob  = (u16*)p;   p += (size_t)NL_ * DM_ * KP_ * 2;      //    268,800
  char* S   = p;                                                // chunk scratch
  size_t fixedB = (size_t)(S - (char*)d_ws);
  // per-token scratch: max(hb 1600B, qkv 2400B + ob 448B) = 2848B
  int NC = 1;
  while (NC < 16 && fixedB + (size_t)(NTOK / NC) * 2848 > ws_size) NC <<= 1;
  if (fixedB + (size_t)(NTOK / NC) * 2848 > ws_size) return;
  const int chunkTok = NTOK / NC;       // multiple of 1024
  const int bc       = B_ / NC;         // batches per chunk (>=2)

  u16* hb     = (u16*)S;                         // [chunkTok][800] bf16
  float* qkv  = (float*)S;                       // [chunkTok][600] fp32
  u16* ob     = (u16*)(S + (size_t)chunkTok * QKVD * 4);  // [chunkTok][KP_] bf16
  float* y    = out;                             // [NTOK][200] fp32, aliases d_out

  embed_kernel<<<NTOK / 4, 256, 0, stream>>>(we, ee, te, pt, bias, wseq, eseq, tseq, pseq,
                                             x, xb);
  {
    int n1 = NL_ * DFF_ * KP_;
    castpad_kernel<<<(n1 + 255) / 256, 256, 0, stream>>>(ffn_w1, W1b, NL_ * DFF_, DM_, KP_);
    int n2 = NL_ * DM_ * DFF_;
    castpad_kernel<<<(n2 + 255) / 256, 256, 0, stream>>>(ffn_w2, W2b, NL_ * DM_, DFF_, DFF_);
    int n3 = NL_ * QKVD * KP_;
    repack_qkv_kernel<<<(n3 + 255) / 256, 256, 0, stream>>>(w_qs, w_ks, w_vs, Wqb);
    int n4 = NL_ * DM_ * KP_;
    castpad_kernel<<<(n4 + 255) / 256, 256, 0, stream>>>(w_o, Wob, NL_ * DM_, DM_, KP_);
  }

  dim3 gF1(chunkTok / 128, (DFF_ + 127) / 128);
  dim3 gF2(chunkTok / 128, (DM_ + 127) / 128);
  dim3 gQK(chunkTok / 128, (QKVD + 127) / 128);
  dim3 gAttn(L_ / 32, H_, bc);

  for (int i = 0; i < NL_; ++i) {
    for (int c = 0; c < NC; ++c) {
      size_t t0 = (size_t)c * chunkTok;
      mfma_gemm<1, 1, 1><<<gF1, 256, 0, stream>>>(xb + t0 * KP_,
          W1b + (size_t)i * DFF_ * KP_, ffn_b1 + i * DFF_, hb, DFF_, KP_);
      mfma_gemm<1, 0, 0><<<gF2, 256, 0, stream>>>(hb,
          W2b + (size_t)i * DM_ * DFF_, ffn_b2 + i * DM_, y + t0 * DM_, DM_, DFF_);
      add_ln_kernel<<<chunkTok / 4, 256, 0, stream>>>(y + t0 * DM_, x + t0 * DM_,
          ln_ffn_a + i * DM_, ln_ffn_b + i * DM_, x + t0 * DM_, xb + t0 * KP_);
    }
    for (int c = 0; c < NC; ++c) {
      size_t t0 = (size_t)c * chunkTok;
      mfma_gemm<0, 0, 0><<<gQK, 256, 0, stream>>>(xb + t0 * KP_,
          Wqb + (size_t)i * QKVD * KP_, nullptr, qkv, QKVD, KP_);
      attn_mfma_kernel<<<gAttn, 256, 0, stream>>>(qkv, wseq + t0, ob);
      mfma_gemm<0, 0, 0><<<gF2, 256, 0, stream>>>(ob,
          Wob + (size_t)i * DM_ * KP_, nullptr, y + t0 * DM_, DM_, KP_);
      add_ln_kernel<<<chunkTok / 4, 256, 0, stream>>>(y + t0 * DM_, x + t0 * DM_,
          ln_attn_a + i * DM_, ln_attn_b + i * DM_,
          ((i == NL_ - 1) ? out : x) + t0 * DM_, xb + t0 * KP_);
    }
  }
}

// Round 10
// 611.692 us; speedup vs baseline: 2.3516x; 1.2460x over previous
//
#include <hip/hip_runtime.h>
#include <math.h>

#define B_ 32
#define L_ 512
#define NTOK 16384      // B_*L_
#define NL_ 3
#define H_ 8
#define DK_ 25
#define DV_ 25
#define DM_ 200
#define DFF_ 800
#define QKVD 600        // H_*DK_*3
#define WD_ 150
#define TD_ 50
#define KP_ 224         // DM_ padded to multiple of 32

typedef unsigned short u16;
typedef short bf16x8 __attribute__((ext_vector_type(8)));   // bf16 bits in shorts (guide §3)
typedef float f32x4 __attribute__((ext_vector_type(4)));

__device__ __forceinline__ u16 f2bf(float v) {
  union { float f; unsigned u; } x; x.f = v;
  unsigned r = x.u + 0x7fffu + ((x.u >> 16) & 1u);
  return (u16)(r >> 16);
}

__device__ __forceinline__ float wave_sum(float v) {
#pragma unroll
  for (int off = 32; off > 0; off >>= 1) v += __shfl_xor(v, off, 64);
  return v;
}

// ---------------- embedding + bias + positional -> x fp32 and xb bf16[KP_] ----------------
__global__ __launch_bounds__(256) void embed_kernel(
    const float* __restrict__ we, const float* __restrict__ ee, const float* __restrict__ te,
    const float* __restrict__ pt, const float* __restrict__ bias,
    const int* __restrict__ wseq, const int* __restrict__ eseq, const int* __restrict__ tseq,
    const int* __restrict__ pseq, float* __restrict__ x, u16* __restrict__ xb) {
  int t = blockIdx.x * 4 + (threadIdx.x >> 6);
  int lane = threadIdx.x & 63;
  const float* wr = we + (size_t)wseq[t] * WD_;
  const float* er = ee + (size_t)eseq[t] * WD_;
  const float* tr = te + (size_t)tseq[t] * TD_;
  const float* pr = pt + (size_t)pseq[t] * DM_;
  float* xr = x + (size_t)t * DM_;
  u16* xbr = xb + (size_t)t * KP_;
#pragma unroll
  for (int d0 = 0; d0 < 256; d0 += 64) {
    int d = d0 + lane;
    if (d < DM_) {
      float v = (d < WD_) ? (wr[d] + er[d]) : tr[d - WD_];
      v = v + bias[d] + pr[d];
      xr[d] = v;
      xbr[d] = f2bf(v);
    } else if (d < KP_) {
      xbr[d] = 0;
    }
  }
}

// ---------------- generic fp32 [rows][kin] -> bf16 [rows][kout] (zero-pad) ----------------
__global__ __launch_bounds__(256) void castpad_kernel(
    const float* __restrict__ src, u16* __restrict__ dst, int rows, int kin, int kout) {
  int idx = blockIdx.x * 256 + threadIdx.x;
  if (idx >= rows * kout) return;
  int r = idx / kout, c = idx - r * kout;
  dst[idx] = (c < kin) ? f2bf(src[(size_t)r * kin + c]) : (u16)0;
}

// ---------------- pack+cast w_qs/w_ks/w_vs -> bf16 [NL][600][KP_] ----------------
__global__ __launch_bounds__(256) void repack_qkv_kernel(
    const float* __restrict__ wq, const float* __restrict__ wk, const float* __restrict__ wv,
    u16* __restrict__ Wp) {
  int idx = blockIdx.x * 256 + threadIdx.x;
  if (idx >= NL_ * QKVD * KP_) return;
  int d = idx % KP_;
  int c = (idx / KP_) % QKVD;
  int i = idx / (KP_ * QKVD);
  if (d >= DM_) { Wp[idx] = 0; return; }
  const float* src = wq; int cc = c;
  if (c >= 400)      { src = wv; cc = c - 400; }
  else if (c >= 200) { src = wk; cc = c - 200; }
  int h = cc / DK_, kk = cc % DK_;
  Wp[idx] = f2bf(src[(((size_t)i * H_ + h) * DM_ + d) * DK_ + kk]);
}

// -------- zero pad rows d=25..31 of VTh (once per call; region never overwritten) --------
__global__ __launch_bounds__(256) void zero_vtpad_kernel(u16* __restrict__ VTh, int total) {
  int idx = blockIdx.x * 256 + threadIdx.x;   // total = bc*8*7*512
  if (idx >= total) return;
  int t = idx & 511;
  int ri = idx >> 9;
  int bh = ri / 7, d = 25 + ri - (bh * 7);
  VTh[((size_t)bh * 32 + d) * 512 + t] = 0;
}

// -------- zero pad cols d=25..31 of Qh,Kh (per layer; region aliases FFN scratch) --------
__global__ __launch_bounds__(256) void zero_qkpad_kernel(
    u16* __restrict__ Qh, u16* __restrict__ Kh) {
  int r = blockIdx.x * 256 + threadIdx.x;    // grid covers chunkTok*8 rows
  u16* qa = Qh + (size_t)r * 32;
  u16* ka = Kh + (size_t)r * 32;
#pragma unroll
  for (int d = 25; d < 32; ++d) { qa[d] = 0; ka[d] = 0; }
}

// ---------------- MFMA GEMM: C[rows][M] = A[rows][Ka](bf16) * W[M][Ka](bf16)^T ----------
#define LDS_LD 40
template<int BIAS, int RELU, int BF16OUT>
__global__ __launch_bounds__(256) void mfma_gemm(
    const u16* __restrict__ A, const u16* __restrict__ W,
    const float* __restrict__ bias, void* __restrict__ Cv, int M, int Ka) {
  __shared__ __align__(16) u16 As[128 * LDS_LD];
  __shared__ __align__(16) u16 Ws[128 * LDS_LD];
  int row0 = blockIdx.x * 128;
  int col0 = blockIdx.y * 128;
  int tid = threadIdx.x;
  int w = tid >> 6, l = tid & 63;
  int wr = w >> 1, wc = w & 1;

  int ch0 = w * 64 + l, ch1 = ch0 + 256;
  int r0 = ch0 >> 2, c0 = ch0 & 3;
  int r1 = ch1 >> 2, c1 = ch1 & 3;
  const u16* Ab0 = A + (size_t)(row0 + r0) * Ka + c0 * 8;
  const u16* Ab1 = A + (size_t)(row0 + r1) * Ka + c1 * 8;
  int wr0 = col0 + r0; if (wr0 >= M) wr0 = M - 1;
  int wr1 = col0 + r1; if (wr1 >= M) wr1 = M - 1;
  const u16* Wb0 = W + (size_t)wr0 * Ka + c0 * 8;
  const u16* Wb1 = W + (size_t)wr1 * Ka + c1 * 8;
  u16* dA0 = As + r0 * LDS_LD + c0 * 8;
  u16* dA1 = As + r1 * LDS_LD + c1 * 8;
  u16* dW0 = Ws + r0 * LDS_LD + c0 * 8;
  u16* dW1 = Ws + r1 * LDS_LD + c1 * 8;

  int k8 = l >> 4, lr = l & 15;
  int a_off[4], w_off[4];
#pragma unroll
  for (int m = 0; m < 4; ++m) {
    a_off[m] = (wr * 64 + m * 16 + lr) * LDS_LD + k8 * 8;
    w_off[m] = (wc * 64 + m * 16 + lr) * LDS_LD + k8 * 8;
  }

  f32x4 acc[4][4];
#pragma unroll
  for (int m = 0; m < 4; ++m)
#pragma unroll
    for (int n = 0; n < 4; ++n) acc[m][n] = (f32x4){0.f, 0.f, 0.f, 0.f};

  int nk = Ka >> 5;
  for (int ks = 0; ks < nk; ++ks) {
    int k0 = ks * 32;
    uint4 va0 = *(const uint4*)(Ab0 + k0);
    uint4 va1 = *(const uint4*)(Ab1 + k0);
    uint4 vw0 = *(const uint4*)(Wb0 + k0);
    uint4 vw1 = *(const uint4*)(Wb1 + k0);
    __syncthreads();
    *(uint4*)dA0 = va0;
    *(uint4*)dA1 = va1;
    *(uint4*)dW0 = vw0;
    *(uint4*)dW1 = vw1;
    __syncthreads();
    bf16x8 af[4], wf[4];
#pragma unroll
    for (int m = 0; m < 4; ++m) af[m] = *(const bf16x8*)(As + a_off[m]);
#pragma unroll
    for (int n = 0; n < 4; ++n) wf[n] = *(const bf16x8*)(Ws + w_off[n]);
#pragma unroll
    for (int m = 0; m < 4; ++m)
#pragma unroll
      for (int n = 0; n < 4; ++n)
        acc[m][n] = __builtin_amdgcn_mfma_f32_16x16x32_bf16(af[m], wf[n], acc[m][n], 0, 0, 0);
  }

#pragma unroll
  for (int n = 0; n < 4; ++n) {
    int col = col0 + wc * 64 + n * 16 + lr;
    if (col >= M) continue;
    float bb = BIAS ? bias[col] : 0.f;
#pragma unroll
    for (int m = 0; m < 4; ++m) {
      int rbase = row0 + wr * 64 + m * 16 + k8 * 4;
#pragma unroll
      for (int j = 0; j < 4; ++j) {
        float v = acc[m][n][j] + bb;
        if (RELU) v = fmaxf(v, 0.f);
        if (BF16OUT) ((u16*)Cv)[(size_t)(rbase + j) * M + col] = f2bf(v);
        else ((float*)Cv)[(size_t)(rbase + j) * M + col] = v;
      }
    }
  }
}

// ------- QKV GEMM: same core, epilogue scatters to Qh[bh][512][32] (pre-scaled by invt),
// ------- Kh[bh][512][32], VTh[bh][32][512] (transpose free: rows j are contiguous tokens)
__global__ __launch_bounds__(256) void mfma_gemm_qkv(
    const u16* __restrict__ A, const u16* __restrict__ W,
    u16* __restrict__ Qh, u16* __restrict__ Kh, u16* __restrict__ VTh) {
  const int M = QKVD, Ka = KP_;
  __shared__ __align__(16) u16 As[128 * LDS_LD];
  __shared__ __align__(16) u16 Ws[128 * LDS_LD];
  int row0 = blockIdx.x * 128;
  int col0 = blockIdx.y * 128;
  int tid = threadIdx.x;
  int w = tid >> 6, l = tid & 63;
  int wr = w >> 1, wc = w & 1;

  int ch0 = w * 64 + l, ch1 = ch0 + 256;
  int r0 = ch0 >> 2, c0 = ch0 & 3;
  int r1 = ch1 >> 2, c1 = ch1 & 3;
  const u16* Ab0 = A + (size_t)(row0 + r0) * Ka + c0 * 8;
  const u16* Ab1 = A + (size_t)(row0 + r1) * Ka + c1 * 8;
  int wr0 = col0 + r0; if (wr0 >= M) wr0 = M - 1;
  int wr1 = col0 + r1; if (wr1 >= M) wr1 = M - 1;
  const u16* Wb0 = W + (size_t)wr0 * Ka + c0 * 8;
  const u16* Wb1 = W + (size_t)wr1 * Ka + c1 * 8;
  u16* dA0 = As + r0 * LDS_LD + c0 * 8;
  u16* dA1 = As + r1 * LDS_LD + c1 * 8;
  u16* dW0 = Ws + r0 * LDS_LD + c0 * 8;
  u16* dW1 = Ws + r1 * LDS_LD + c1 * 8;

  int k8 = l >> 4, lr = l & 15;
  int a_off[4], w_off[4];
#pragma unroll
  for (int m = 0; m < 4; ++m) {
    a_off[m] = (wr * 64 + m * 16 + lr) * LDS_LD + k8 * 8;
    w_off[m] = (wc * 64 + m * 16 + lr) * LDS_LD + k8 * 8;
  }

  f32x4 acc[4][4];
#pragma unroll
  for (int m = 0; m < 4; ++m)
#pragma unroll
    for (int n = 0; n < 4; ++n) acc[m][n] = (f32x4){0.f, 0.f, 0.f, 0.f};

  for (int ks = 0; ks < (KP_ >> 5); ++ks) {
    int k0 = ks * 32;
    uint4 va0 = *(const uint4*)(Ab0 + k0);
    uint4 va1 = *(const uint4*)(Ab1 + k0);
    uint4 vw0 = *(const uint4*)(Wb0 + k0);
    uint4 vw1 = *(const uint4*)(Wb1 + k0);
    __syncthreads();
    *(uint4*)dA0 = va0;
    *(uint4*)dA1 = va1;
    *(uint4*)dW0 = vw0;
    *(uint4*)dW1 = vw1;
    __syncthreads();
    bf16x8 af[4], wf[4];
#pragma unroll
    for (int m = 0; m < 4; ++m) af[m] = *(const bf16x8*)(As + a_off[m]);
#pragma unroll
    for (int n = 0; n < 4; ++n) wf[n] = *(const bf16x8*)(Ws + w_off[n]);
#pragma unroll
    for (int m = 0; m < 4; ++m)
#pragma unroll
      for (int n = 0; n < 4; ++n)
        acc[m][n] = __builtin_amdgcn_mfma_f32_16x16x32_bf16(af[m], wf[n], acc[m][n], 0, 0, 0);
  }

  const float invt = 0.07071067811865475f;   // 1/sqrt(200) folded into Q
#pragma unroll
  for (int n = 0; n < 4; ++n) {
    int col = col0 + wc * 64 + n * 16 + lr;
    if (col >= M) continue;
    int sec = (col >= 400) ? 2 : ((col >= 200) ? 1 : 0);
    int cc = col - sec * 200;
    int h = cc / 25, d = cc - h * 25;
#pragma unroll
    for (int m = 0; m < 4; ++m) {
      int rbase = row0 + wr * 64 + m * 16 + k8 * 4;
#pragma unroll
      for (int j = 0; j < 4; ++j) {
        int tok = rbase + j;
        int bl = tok >> 9, tl = tok & 511;
        size_t bh = (size_t)bl * 8 + h;
        float v = acc[m][n][j];
        if (sec == 0)      Qh[(bh * 512 + tl) * 32 + d] = f2bf(v * invt);
        else if (sec == 1) Kh[(bh * 512 + tl) * 32 + d] = f2bf(v);
        else               VTh[(bh * 32 + d) * 512 + tl] = f2bf(v);
      }
    }
  }
}

// ---------------- flash MFMA attention v2: zero staging, direct global frags ----------
// block=(qt,h,b); 4 waves tile 32x32 S quadrants (qh=w>>1, kh=w&1). 2 barriers/kt.
__global__ __launch_bounds__(256) void attn_mfma2_kernel(
    const u16* __restrict__ Qh, const u16* __restrict__ Kh, const u16* __restrict__ VTh,
    const int* __restrict__ wseq, u16* __restrict__ ob) {
  __shared__ __align__(16) float S32[32 * 36];
  __shared__ __align__(8) u16 Ps[32 * 40];
  __shared__ float maskadd[512];
  __shared__ float mrun[32], ssum[32], rbuf[32];

  int qt = blockIdx.x, h = blockIdx.y, b = blockIdx.z;
  int tid = threadIdx.x;
  int w = tid >> 6, l = tid & 63;
  int qh = w >> 1, kh = w & 1;
  int lr = l & 15, k8 = l >> 4;
  size_t bh = (size_t)b * 8 + h;

  maskadd[tid]       = (wseq[b * L_ + tid] == 0)       ? -1e30f : 0.f;
  maskadd[tid + 256] = (wseq[b * L_ + tid + 256] == 0) ? -1e30f : 0.f;
  if (tid < 32) { mrun[tid] = -3.0e38f; ssum[tid] = 0.f; }
  __syncthreads();

  bf16x8 qf = *(const bf16x8*)(Qh + (bh * 512 + qt * 32 + qh * 16 + lr) * 32 + k8 * 8);
  const u16* Kp = Kh + bh * 512 * 32;
  const u16* Vp = VTh + bh * 32 * 512;
  f32x4 oacc = (f32x4){0.f, 0.f, 0.f, 0.f};

  for (int kt = 0; kt < 16; ++kt) {
    bf16x8 kf = *(const bf16x8*)(Kp + (kt * 32 + kh * 16 + lr) * 32 + k8 * 8);
    bf16x8 vf = *(const bf16x8*)(Vp + (kh * 16 + lr) * 512 + kt * 32 + k8 * 8);
    f32x4 sf = (f32x4){0.f, 0.f, 0.f, 0.f};
    sf = __builtin_amdgcn_mfma_f32_16x16x32_bf16(qf, kf, sf, 0, 0, 0);
    int colg = kh * 16 + lr;
    float ma = maskadd[kt * 32 + colg];
#pragma unroll
    for (int j = 0; j < 4; ++j)
      S32[(qh * 16 + k8 * 4 + j) * 36 + colg] = sf[j] + ma;   // invt pre-folded into Q
    __syncthreads();

    {   // online softmax: row = tid>>3 (wave-local), seg = tid&7 covers 4 cols
      int row = tid >> 3, seg = tid & 7;
      f32x4 sv = *(const f32x4*)(S32 + row * 36 + seg * 4);
      float lm = fmaxf(fmaxf(sv[0], sv[1]), fmaxf(sv[2], sv[3]));
      lm = fmaxf(lm, __shfl_xor(lm, 1, 64));
      lm = fmaxf(lm, __shfl_xor(lm, 2, 64));
      lm = fmaxf(lm, __shfl_xor(lm, 4, 64));
      float om = mrun[row];
      float nm = fmaxf(om, lm);
      float r = __expf(om - nm);
      float p0 = __expf(sv[0] - nm), p1 = __expf(sv[1] - nm);
      float p2 = __expf(sv[2] - nm), p3 = __expf(sv[3] - nm);
      float ls = (p0 + p1) + (p2 + p3);
      ls += __shfl_xor(ls, 1, 64);
      ls += __shfl_xor(ls, 2, 64);
      ls += __shfl_xor(ls, 4, 64);
      if (seg == 0) { mrun[row] = nm; ssum[row] = ssum[row] * r + ls; rbuf[row] = r; }
      uint2 pw;
      pw.x = (unsigned)f2bf(p0) | ((unsigned)f2bf(p1) << 16);
      pw.y = (unsigned)f2bf(p2) | ((unsigned)f2bf(p3) << 16);
      *(uint2*)(Ps + row * 40 + seg * 4) = pw;
    }
    __syncthreads();

    // rescale + PV: O[q][v] += P[q][key] * VT[v][key]
#pragma unroll
    for (int j = 0; j < 4; ++j) oacc[j] *= rbuf[qh * 16 + k8 * 4 + j];
    bf16x8 pf = *(const bf16x8*)(Ps + (qh * 16 + lr) * 40 + k8 * 8);
    oacc = __builtin_amdgcn_mfma_f32_16x16x32_bf16(pf, vf, oacc, 0, 0, 0);
    // Ps reads drain before next softmax write (barrier after next S32 write)
  }

  {   // write O: col v=kh*16+lr, rows qh*16+k8*4+j
    int v = kh * 16 + lr;
    if (v < DV_) {
#pragma unroll
      for (int j = 0; j < 4; ++j) {
        int row = qh * 16 + k8 * 4 + j;
        float inv = 1.f / ssum[row];
        int tok = qt * 32 + row;
        ob[(size_t)(b * L_ + tok) * KP_ + h * DV_ + v] = f2bf(oacc[j] * inv);
      }
    }
  }
  if (h == H_ - 1) {                    // zero K-pad cols 200..223 for this q-tile
    for (int idx = tid; idx < 32 * (KP_ - DM_); idx += 256) {
      int row = idx / (KP_ - DM_), c = idx % (KP_ - DM_);
      ob[(size_t)(b * L_ + qt * 32 + row) * KP_ + DM_ + c] = 0;
    }
  }
}

// ------- x_out = LayerNorm(y + x_in) (unbiased var, eps on sigma); also writes bf16 xb ----
__global__ __launch_bounds__(256) void add_ln_kernel(
    const float* __restrict__ y, const float* __restrict__ xin,
    const float* __restrict__ a, const float* __restrict__ bpar,
    float* __restrict__ xout, u16* __restrict__ xb) {
  int t = blockIdx.x * 4 + (threadIdx.x >> 6);
  int lane = threadIdx.x & 63;
  const float* yr = y + (size_t)t * DM_;
  const float* xr = xin + (size_t)t * DM_;
  float z0 = yr[lane] + xr[lane];
  float z1 = yr[lane + 64] + xr[lane + 64];
  float z2 = yr[lane + 128] + xr[lane + 128];
  float z3 = (lane < 8) ? (yr[lane + 192] + xr[lane + 192]) : 0.f;
  float sum = wave_sum(z0 + z1 + z2 + z3);
  float mu = sum * (1.f / DM_);
  float d0 = z0 - mu, d1 = z1 - mu, d2 = z2 - mu;
  float d3 = (lane < 8) ? (z3 - mu) : 0.f;
  float ss = wave_sum(d0 * d0 + d1 * d1 + d2 * d2 + d3 * d3);
  float inv = 1.f / (sqrtf(ss * (1.f / (DM_ - 1))) + 1e-3f);
  float* xo = xout + (size_t)t * DM_;
  u16* xbr = xb + (size_t)t * KP_;
  float o0 = d0 * inv * a[lane] + bpar[lane];
  float o1 = d1 * inv * a[lane + 64] + bpar[lane + 64];
  float o2 = d2 * inv * a[lane + 128] + bpar[lane + 128];
  xo[lane] = o0;        xbr[lane] = f2bf(o0);
  xo[lane + 64] = o1;   xbr[lane + 64] = f2bf(o1);
  xo[lane + 128] = o2;  xbr[lane + 128] = f2bf(o2);
  if (lane < 8) {
    float o3 = d3 * inv * a[lane + 192] + bpar[lane + 192];
    xo[lane + 192] = o3;
    xbr[lane + 192] = f2bf(o3);
  } else if (lane < 32) {
    xbr[lane + 192] = 0;  // pad cols 200..223
  }
}

extern "C" void kernel_launch(void* const* d_in, const int* in_sizes, int n_in,
                              void* d_out, int out_size, void* d_ws, size_t ws_size,
                              hipStream_t stream) {
  const float* we       = (const float*)d_in[0];
  const float* ee       = (const float*)d_in[1];
  const float* te       = (const float*)d_in[2];
  const float* pt       = (const float*)d_in[3];
  const float* bias     = (const float*)d_in[4];
  const float* w_qs     = (const float*)d_in[5];
  const float* w_ks     = (const float*)d_in[6];
  const float* w_vs     = (const float*)d_in[7];
  const float* w_o      = (const float*)d_in[8];
  const float* ffn_w1   = (const float*)d_in[9];
  const float* ffn_b1   = (const float*)d_in[10];
  const float* ffn_w2   = (const float*)d_in[11];
  const float* ffn_b2   = (const float*)d_in[12];
  const float* ln_ffn_a = (const float*)d_in[13];
  const float* ln_ffn_b = (const float*)d_in[14];
  const float* ln_attn_a= (const float*)d_in[15];
  const float* ln_attn_b= (const float*)d_in[16];
  const int* wseq       = (const int*)d_in[17];
  const int* eseq       = (const int*)d_in[18];
  const int* tseq       = (const int*)d_in[19];
  const int* pseq       = (const int*)d_in[20];
  float* out = (float*)d_out;

  // ---- workspace layout (bytes), adaptive chunking ----
  char* p = (char*)d_ws;
  float* x  = (float*)p; p += (size_t)NTOK * DM_ * 4;           // 13,107,200
  u16* xb   = (u16*)p;   p += (size_t)NTOK * KP_ * 2;           //  7,340,032
  u16* W1b  = (u16*)p;   p += (size_t)NL_ * DFF_ * KP_ * 2;     //  1,075,200
  u16* W2b  = (u16*)p;   p += (size_t)NL_ * DM_ * DFF_ * 2;     //    960,000
  u16* Wqb  = (u16*)p;   p += (size_t)NL_ * QKVD * KP_ * 2;     //    806,400
  u16* Wob  = (u16*)p;   p += (size_t)NL_ * DM_ * KP_ * 2;      //    268,800
  char* S   = p;                                                // chunk scratch
  size_t fixedB = (size_t)(S - (char*)d_ws);
  // per-token scratch: region1 max(hb 1600B, Qh+Kh 1024B) + region2 (VTh 512 + ob 448)
  int NC = 1;
  while (NC < 16 && fixedB + (size_t)(NTOK / NC) * 2560 > ws_size) NC <<= 1;
  if (fixedB + (size_t)(NTOK / NC) * 2560 > ws_size) return;
  const int chunkTok = NTOK / NC;       // multiple of 1024
  const int bc       = B_ / NC;         // batches per chunk (>=2)

  u16* hb  = (u16*)S;                              // [chunkTok][800] bf16 (FFN)
  u16* Qh  = (u16*)S;                              // [bc*8][512][32] bf16 (aliases hb)
  u16* Kh  = Qh + (size_t)chunkTok * 256;          // [bc*8][512][32]
  char* R2 = S + (size_t)chunkTok * 1600;
  u16* VTh = (u16*)R2;                             // [bc*8][32][512]
  u16* ob  = VTh + (size_t)chunkTok * 256;         // [chunkTok][KP_]
  float* y = out;                                  // [NTOK][200] fp32, aliases d_out

  embed_kernel<<<NTOK / 4, 256, 0, stream>>>(we, ee, te, pt, bias, wseq, eseq, tseq, pseq,
                                             x, xb);
  {
    int n1 = NL_ * DFF_ * KP_;
    castpad_kernel<<<(n1 + 255) / 256, 256, 0, stream>>>(ffn_w1, W1b, NL_ * DFF_, DM_, KP_);
    int n2 = NL_ * DM_ * DFF_;
    castpad_kernel<<<(n2 + 255) / 256, 256, 0, stream>>>(ffn_w2, W2b, NL_ * DM_, DFF_, DFF_);
    int n3 = NL_ * QKVD * KP_;
    repack_qkv_kernel<<<(n3 + 255) / 256, 256, 0, stream>>>(w_qs, w_ks, w_vs, Wqb);
    int n4 = NL_ * DM_ * KP_;
    castpad_kernel<<<(n4 + 255) / 256, 256, 0, stream>>>(w_o, Wob, NL_ * DM_, DM_, KP_);
    int nv = bc * 8 * 7 * 512;
    zero_vtpad_kernel<<<(nv + 255) / 256, 256, 0, stream>>>(VTh, nv);
  }

  dim3 gF1(chunkTok / 128, (DFF_ + 127) / 128);
  dim3 gF2(chunkTok / 128, (DM_ + 127) / 128);
  dim3 gQK(chunkTok / 128, (QKVD + 127) / 128);
  dim3 gAttn(L_ / 32, H_, bc);

  for (int i = 0; i < NL_; ++i) {
    for (int c = 0; c < NC; ++c) {
      size_t t0 = (size_t)c * chunkTok;
      mfma_gemm<1, 1, 1><<<gF1, 256, 0, stream>>>(xb + t0 * KP_,
          W1b + (size_t)i * DFF_ * KP_, ffn_b1 + i * DFF_, hb, DFF_, KP_);
      mfma_gemm<1, 0, 0><<<gF2, 256, 0, stream>>>(hb,
          W2b + (size_t)i * DM_ * DFF_, ffn_b2 + i * DM_, y + t0 * DM_, DM_, DFF_);
      add_ln_kernel<<<chunkTok / 4, 256, 0, stream>>>(y + t0 * DM_, x + t0 * DM_,
          ln_ffn_a + i * DM_, ln_ffn_b + i * DM_, x + t0 * DM_, xb + t0 * KP_);
    }
    for (int c = 0; c < NC; ++c) {
      size_t t0 = (size_t)c * chunkTok;
      zero_qkpad_kernel<<<chunkTok * 8 / 256, 256, 0, stream>>>(Qh, Kh);
      mfma_gemm_qkv<<<gQK, 256, 0, stream>>>(xb + t0 * KP_,
          Wqb + (size_t)i * QKVD * KP_, Qh, Kh, VTh);
      attn_mfma2_kernel<<<gAttn, 256, 0, stream>>>(Qh, Kh, VTh, wseq + t0, ob);
      mfma_gemm<0, 0, 0><<<gF2, 256, 0, stream>>>(ob,
          Wob + (size_t)i * DM_ * KP_, nullptr, y + t0 * DM_, DM_, KP_);
      add_ln_kernel<<<chunkTok / 4, 256, 0, stream>>>(y + t0 * DM_, x + t0 * DM_,
          ln_attn_a + i * DM_, ln_attn_b + i * DM_,
          ((i == NL_ - 1) ? out : x) + t0 * DM_, xb + t0 * KP_);
    }
  }
}

// Round 11
// 600.917 us; speedup vs baseline: 2.3938x; 1.0179x over previous
//
#include <hip/hip_runtime.h>
#include <math.h>

#define B_ 32
#define L_ 512
#define NTOK 16384      // B_*L_
#define NL_ 3
#define H_ 8
#define DK_ 25
#define DV_ 25
#define DM_ 200
#define DFF_ 800
#define QKVD 600        // H_*DK_*3
#define WD_ 150
#define TD_ 50
#define KP_ 224         // DM_ padded to multiple of 32

typedef unsigned short u16;
typedef short bf16x8 __attribute__((ext_vector_type(8)));   // bf16 bits in shorts (guide §3)
typedef float f32x4 __attribute__((ext_vector_type(4)));

__device__ __forceinline__ u16 f2bf(float v) {
  union { float f; unsigned u; } x; x.f = v;
  unsigned r = x.u + 0x7fffu + ((x.u >> 16) & 1u);
  return (u16)(r >> 16);
}

__device__ __forceinline__ float wave_sum(float v) {
#pragma unroll
  for (int off = 32; off > 0; off >>= 1) v += __shfl_xor(v, off, 64);
  return v;
}

// ---------------- embedding + bias + positional -> x fp32 and xb bf16[KP_] ----------------
__global__ __launch_bounds__(256) void embed_kernel(
    const float* __restrict__ we, const float* __restrict__ ee, const float* __restrict__ te,
    const float* __restrict__ pt, const float* __restrict__ bias,
    const int* __restrict__ wseq, const int* __restrict__ eseq, const int* __restrict__ tseq,
    const int* __restrict__ pseq, float* __restrict__ x, u16* __restrict__ xb) {
  int t = blockIdx.x * 4 + (threadIdx.x >> 6);
  int lane = threadIdx.x & 63;
  const float* wr = we + (size_t)wseq[t] * WD_;
  const float* er = ee + (size_t)eseq[t] * WD_;
  const float* tr = te + (size_t)tseq[t] * TD_;
  const float* pr = pt + (size_t)pseq[t] * DM_;
  float* xr = x + (size_t)t * DM_;
  u16* xbr = xb + (size_t)t * KP_;
#pragma unroll
  for (int d0 = 0; d0 < 256; d0 += 64) {
    int d = d0 + lane;
    if (d < DM_) {
      float v = (d < WD_) ? (wr[d] + er[d]) : tr[d - WD_];
      v = v + bias[d] + pr[d];
      xr[d] = v;
      xbr[d] = f2bf(v);
    } else if (d < KP_) {
      xbr[d] = 0;
    }
  }
}

// ---------------- generic fp32 [rows][kin] -> bf16 [rows][kout] (zero-pad) ----------------
__global__ __launch_bounds__(256) void castpad_kernel(
    const float* __restrict__ src, u16* __restrict__ dst, int rows, int kin, int kout) {
  int idx = blockIdx.x * 256 + threadIdx.x;
  if (idx >= rows * kout) return;
  int r = idx / kout, c = idx - r * kout;
  dst[idx] = (c < kin) ? f2bf(src[(size_t)r * kin + c]) : (u16)0;
}

// ---------------- pack+cast w_qs/w_ks/w_vs -> bf16 [NL][600][KP_] ----------------
__global__ __launch_bounds__(256) void repack_qkv_kernel(
    const float* __restrict__ wq, const float* __restrict__ wk, const float* __restrict__ wv,
    u16* __restrict__ Wp) {
  int idx = blockIdx.x * 256 + threadIdx.x;
  if (idx >= NL_ * QKVD * KP_) return;
  int d = idx % KP_;
  int c = (idx / KP_) % QKVD;
  int i = idx / (KP_ * QKVD);
  if (d >= DM_) { Wp[idx] = 0; return; }
  const float* src = wq; int cc = c;
  if (c >= 400)      { src = wv; cc = c - 400; }
  else if (c >= 200) { src = wk; cc = c - 200; }
  int h = cc / DK_, kk = cc % DK_;
  Wp[idx] = f2bf(src[(((size_t)i * H_ + h) * DM_ + d) * DK_ + kk]);
}

// -------- zero pad rows d=25..31 of VTh (once per call; region never overwritten) --------
__global__ __launch_bounds__(256) void zero_vtpad_kernel(u16* __restrict__ VTh, int total) {
  int idx = blockIdx.x * 256 + threadIdx.x;   // total = bc*8*7*512
  if (idx >= total) return;
  int t = idx & 511;
  int ri = idx >> 9;
  int bh = ri / 7, d = 25 + ri - (bh * 7);
  VTh[((size_t)bh * 32 + d) * 512 + t] = 0;
}

// -------- zero pad cols d=25..31 of Qh,Kh (per layer; region aliases FFN scratch) --------
__global__ __launch_bounds__(256) void zero_qkpad_kernel(
    u16* __restrict__ Qh, u16* __restrict__ Kh) {
  int r = blockIdx.x * 256 + threadIdx.x;    // grid covers chunkTok*8 rows
  u16* qa = Qh + (size_t)r * 32;
  u16* ka = Kh + (size_t)r * 32;
#pragma unroll
  for (int d = 25; d < 32; ++d) { qa[d] = 0; ka[d] = 0; }
}

// ---------------- MFMA GEMM: C[rows][M] = A[rows][Ka](bf16) * W[M][Ka](bf16)^T ----------
// BN=128: 4 waves 2x2, wave tile 64x64 (proven path). BN=64: 4 waves 2x2, wave 64x32 —
// grid.y doubles so narrow-M GEMMs (M=200) get 2 blocks/CU instead of 1.
#define LDS_LD 40
template<int BN, int BIAS, int RELU, int BF16OUT>
__global__ __launch_bounds__(256) void mfma_gemm(
    const u16* __restrict__ A, const u16* __restrict__ W,
    const float* __restrict__ bias, void* __restrict__ Cv, int M, int Ka) {
  constexpr int NF = BN / 32;            // col frags per wave (4 or 2)
  __shared__ __align__(16) u16 As[128 * LDS_LD];
  __shared__ __align__(16) u16 Ws[BN * LDS_LD];
  int row0 = blockIdx.x * 128;
  int col0 = blockIdx.y * BN;
  int tid = threadIdx.x;
  int w = tid >> 6, l = tid & 63;
  int wr = w >> 1, wc = w & 1;

  // A staging: 512 chunks (16B), 2 per thread
  int ra0 = tid >> 2, ca0 = tid & 3;
  int ch1 = tid + 256;
  int ra1 = ch1 >> 2, ca1 = ch1 & 3;
  const u16* Ab0 = A + (size_t)(row0 + ra0) * Ka + ca0 * 8;
  const u16* Ab1 = A + (size_t)(row0 + ra1) * Ka + ca1 * 8;
  u16* dA0 = As + ra0 * LDS_LD + ca0 * 8;
  u16* dA1 = As + ra1 * LDS_LD + ca1 * 8;

  // W staging: BN*4 chunks; thread handles tid (and tid+256 when BN==128)
  int wrow0 = col0 + ra0; if (wrow0 >= M) wrow0 = M - 1;   // clamp; store-guarded
  const u16* Wb0 = W + (size_t)wrow0 * Ka + ca0 * 8;
  u16* dW0 = Ws + ra0 * LDS_LD + ca0 * 8;
  const u16* Wb1 = nullptr; u16* dW1 = nullptr;
  if constexpr (BN == 128) {
    int wrow1 = col0 + ra1; if (wrow1 >= M) wrow1 = M - 1;
    Wb1 = W + (size_t)wrow1 * Ka + ca1 * 8;
    dW1 = Ws + ra1 * LDS_LD + ca1 * 8;
  }

  int k8 = l >> 4, lr = l & 15;
  int a_off[4], w_off[NF];
#pragma unroll
  for (int m = 0; m < 4; ++m)
    a_off[m] = (wr * 64 + m * 16 + lr) * LDS_LD + k8 * 8;
#pragma unroll
  for (int n = 0; n < NF; ++n)
    w_off[n] = (wc * (BN / 2) + n * 16 + lr) * LDS_LD + k8 * 8;

  f32x4 acc[4][NF];
#pragma unroll
  for (int m = 0; m < 4; ++m)
#pragma unroll
    for (int n = 0; n < NF; ++n) acc[m][n] = (f32x4){0.f, 0.f, 0.f, 0.f};

  int nk = Ka >> 5;
  for (int ks = 0; ks < nk; ++ks) {
    int k0 = ks * 32;
    uint4 va0 = *(const uint4*)(Ab0 + k0);
    uint4 va1 = *(const uint4*)(Ab1 + k0);
    uint4 vw0 = *(const uint4*)(Wb0 + k0);
    uint4 vw1 = make_uint4(0, 0, 0, 0);
    if constexpr (BN == 128) vw1 = *(const uint4*)(Wb1 + k0);
    __syncthreads();
    *(uint4*)dA0 = va0;
    *(uint4*)dA1 = va1;
    *(uint4*)dW0 = vw0;
    if constexpr (BN == 128) *(uint4*)dW1 = vw1;
    __syncthreads();
    bf16x8 af[4], wf[NF];
#pragma unroll
    for (int m = 0; m < 4; ++m) af[m] = *(const bf16x8*)(As + a_off[m]);
#pragma unroll
    for (int n = 0; n < NF; ++n) wf[n] = *(const bf16x8*)(Ws + w_off[n]);
#pragma unroll
    for (int m = 0; m < 4; ++m)
#pragma unroll
      for (int n = 0; n < NF; ++n)
        acc[m][n] = __builtin_amdgcn_mfma_f32_16x16x32_bf16(af[m], wf[n], acc[m][n], 0, 0, 0);
  }

#pragma unroll
  for (int n = 0; n < NF; ++n) {
    int col = col0 + wc * (BN / 2) + n * 16 + lr;
    if (col >= M) continue;
    float bb = BIAS ? bias[col] : 0.f;
#pragma unroll
    for (int m = 0; m < 4; ++m) {
      int rbase = row0 + wr * 64 + m * 16 + k8 * 4;
#pragma unroll
      for (int j = 0; j < 4; ++j) {
        float v = acc[m][n][j] + bb;
        if (RELU) v = fmaxf(v, 0.f);
        if (BF16OUT) ((u16*)Cv)[(size_t)(rbase + j) * M + col] = f2bf(v);
        else ((float*)Cv)[(size_t)(rbase + j) * M + col] = v;
      }
    }
  }
}

// ------- QKV GEMM: same core, epilogue scatters to Qh[bh][512][32] (pre-scaled by invt),
// ------- Kh[bh][512][32], VTh[bh][32][512] (transpose free: rows j are contiguous tokens)
__global__ __launch_bounds__(256) void mfma_gemm_qkv(
    const u16* __restrict__ A, const u16* __restrict__ W,
    u16* __restrict__ Qh, u16* __restrict__ Kh, u16* __restrict__ VTh) {
  const int M = QKVD, Ka = KP_;
  __shared__ __align__(16) u16 As[128 * LDS_LD];
  __shared__ __align__(16) u16 Ws[128 * LDS_LD];
  int row0 = blockIdx.x * 128;
  int col0 = blockIdx.y * 128;
  int tid = threadIdx.x;
  int w = tid >> 6, l = tid & 63;
  int wr = w >> 1, wc = w & 1;

  int ch0 = w * 64 + l, ch1 = ch0 + 256;
  int r0 = ch0 >> 2, c0 = ch0 & 3;
  int r1 = ch1 >> 2, c1 = ch1 & 3;
  const u16* Ab0 = A + (size_t)(row0 + r0) * Ka + c0 * 8;
  const u16* Ab1 = A + (size_t)(row0 + r1) * Ka + c1 * 8;
  int wr0 = col0 + r0; if (wr0 >= M) wr0 = M - 1;
  int wr1 = col0 + r1; if (wr1 >= M) wr1 = M - 1;
  const u16* Wb0 = W + (size_t)wr0 * Ka + c0 * 8;
  const u16* Wb1 = W + (size_t)wr1 * Ka + c1 * 8;
  u16* dA0 = As + r0 * LDS_LD + c0 * 8;
  u16* dA1 = As + r1 * LDS_LD + c1 * 8;
  u16* dW0 = Ws + r0 * LDS_LD + c0 * 8;
  u16* dW1 = Ws + r1 * LDS_LD + c1 * 8;

  int k8 = l >> 4, lr = l & 15;
  int a_off[4], w_off[4];
#pragma unroll
  for (int m = 0; m < 4; ++m) {
    a_off[m] = (wr * 64 + m * 16 + lr) * LDS_LD + k8 * 8;
    w_off[m] = (wc * 64 + m * 16 + lr) * LDS_LD + k8 * 8;
  }

  f32x4 acc[4][4];
#pragma unroll
  for (int m = 0; m < 4; ++m)
#pragma unroll
    for (int n = 0; n < 4; ++n) acc[m][n] = (f32x4){0.f, 0.f, 0.f, 0.f};

  for (int ks = 0; ks < (KP_ >> 5); ++ks) {
    int k0 = ks * 32;
    uint4 va0 = *(const uint4*)(Ab0 + k0);
    uint4 va1 = *(const uint4*)(Ab1 + k0);
    uint4 vw0 = *(const uint4*)(Wb0 + k0);
    uint4 vw1 = *(const uint4*)(Wb1 + k0);
    __syncthreads();
    *(uint4*)dA0 = va0;
    *(uint4*)dA1 = va1;
    *(uint4*)dW0 = vw0;
    *(uint4*)dW1 = vw1;
    __syncthreads();
    bf16x8 af[4], wf[4];
#pragma unroll
    for (int m = 0; m < 4; ++m) af[m] = *(const bf16x8*)(As + a_off[m]);
#pragma unroll
    for (int n = 0; n < 4; ++n) wf[n] = *(const bf16x8*)(Ws + w_off[n]);
#pragma unroll
    for (int m = 0; m < 4; ++m)
#pragma unroll
      for (int n = 0; n < 4; ++n)
        acc[m][n] = __builtin_amdgcn_mfma_f32_16x16x32_bf16(af[m], wf[n], acc[m][n], 0, 0, 0);
  }

  const float invt = 0.07071067811865475f;   // 1/sqrt(200) folded into Q
#pragma unroll
  for (int n = 0; n < 4; ++n) {
    int col = col0 + wc * 64 + n * 16 + lr;
    if (col >= M) continue;
    int sec = (col >= 400) ? 2 : ((col >= 200) ? 1 : 0);
    int cc = col - sec * 200;
    int h = cc / 25, d = cc - h * 25;
#pragma unroll
    for (int m = 0; m < 4; ++m) {
      int rbase = row0 + wr * 64 + m * 16 + k8 * 4;
#pragma unroll
      for (int j = 0; j < 4; ++j) {
        int tok = rbase + j;
        int bl = tok >> 9, tl = tok & 511;
        size_t bh = (size_t)bl * 8 + h;
        float v = acc[m][n][j];
        if (sec == 0)      Qh[(bh * 512 + tl) * 32 + d] = f2bf(v * invt);
        else if (sec == 1) Kh[(bh * 512 + tl) * 32 + d] = f2bf(v);
        else               VTh[(bh * 32 + d) * 512 + tl] = f2bf(v);
      }
    }
  }
}

// ---------------- flash MFMA attention v3: XCD-local 1-D grid ----------
// block id = qt*nbh + (b*8+h)  ->  id%8 == h: all (qt,b) blocks of a head share one XCD,
// so its K/V/Q (~3 MB at NC=1) stay resident in that XCD's 4 MB L2.
__global__ __launch_bounds__(256) void attn_mfma3_kernel(
    const u16* __restrict__ Qh, const u16* __restrict__ Kh, const u16* __restrict__ VTh,
    const int* __restrict__ wseq, u16* __restrict__ ob, int nbh) {
  __shared__ __align__(16) float S32[32 * 36];
  __shared__ __align__(8) u16 Ps[32 * 40];
  __shared__ float maskadd[512];
  __shared__ float mrun[32], ssum[32], rbuf[32];

  int id = blockIdx.x;
  int g = id % nbh;
  int qt = id / nbh;
  int b = g >> 3, h = g & 7;
  int tid = threadIdx.x;
  int w = tid >> 6, l = tid & 63;
  int qh = w >> 1, kh = w & 1;
  int lr = l & 15, k8 = l >> 4;
  size_t bh = (size_t)b * 8 + h;

  maskadd[tid]       = (wseq[b * L_ + tid] == 0)       ? -1e30f : 0.f;
  maskadd[tid + 256] = (wseq[b * L_ + tid + 256] == 0) ? -1e30f : 0.f;
  if (tid < 32) { mrun[tid] = -3.0e38f; ssum[tid] = 0.f; }
  __syncthreads();

  bf16x8 qf = *(const bf16x8*)(Qh + (bh * 512 + qt * 32 + qh * 16 + lr) * 32 + k8 * 8);
  const u16* Kp = Kh + bh * 512 * 32;
  const u16* Vp = VTh + bh * 32 * 512;
  f32x4 oacc = (f32x4){0.f, 0.f, 0.f, 0.f};

  for (int kt = 0; kt < 16; ++kt) {
    bf16x8 kf = *(const bf16x8*)(Kp + (kt * 32 + kh * 16 + lr) * 32 + k8 * 8);
    bf16x8 vf = *(const bf16x8*)(Vp + (kh * 16 + lr) * 512 + kt * 32 + k8 * 8);
    f32x4 sf = (f32x4){0.f, 0.f, 0.f, 0.f};
    sf = __builtin_amdgcn_mfma_f32_16x16x32_bf16(qf, kf, sf, 0, 0, 0);
    int colg = kh * 16 + lr;
    float ma = maskadd[kt * 32 + colg];
#pragma unroll
    for (int j = 0; j < 4; ++j)
      S32[(qh * 16 + k8 * 4 + j) * 36 + colg] = sf[j] + ma;   // invt pre-folded into Q
    __syncthreads();

    {   // online softmax: row = tid>>3 (wave-local), seg = tid&7 covers 4 cols
      int row = tid >> 3, seg = tid & 7;
      f32x4 sv = *(const f32x4*)(S32 + row * 36 + seg * 4);
      float lm = fmaxf(fmaxf(sv[0], sv[1]), fmaxf(sv[2], sv[3]));
      lm = fmaxf(lm, __shfl_xor(lm, 1, 64));
      lm = fmaxf(lm, __shfl_xor(lm, 2, 64));
      lm = fmaxf(lm, __shfl_xor(lm, 4, 64));
      float om = mrun[row];
      float nm = fmaxf(om, lm);
      float r = __expf(om - nm);
      float p0 = __expf(sv[0] - nm), p1 = __expf(sv[1] - nm);
      float p2 = __expf(sv[2] - nm), p3 = __expf(sv[3] - nm);
      float ls = (p0 + p1) + (p2 + p3);
      ls += __shfl_xor(ls, 1, 64);
      ls += __shfl_xor(ls, 2, 64);
      ls += __shfl_xor(ls, 4, 64);
      if (seg == 0) { mrun[row] = nm; ssum[row] = ssum[row] * r + ls; rbuf[row] = r; }
      uint2 pw;
      pw.x = (unsigned)f2bf(p0) | ((unsigned)f2bf(p1) << 16);
      pw.y = (unsigned)f2bf(p2) | ((unsigned)f2bf(p3) << 16);
      *(uint2*)(Ps + row * 40 + seg * 4) = pw;
    }
    __syncthreads();

    // rescale + PV: O[q][v] += P[q][key] * VT[v][key]
#pragma unroll
    for (int j = 0; j < 4; ++j) oacc[j] *= rbuf[qh * 16 + k8 * 4 + j];
    bf16x8 pf = *(const bf16x8*)(Ps + (qh * 16 + lr) * 40 + k8 * 8);
    oacc = __builtin_amdgcn_mfma_f32_16x16x32_bf16(pf, vf, oacc, 0, 0, 0);
    // Ps reads drain before next softmax write (barrier after next S32 write)
  }

  {   // write O: col v=kh*16+lr, rows qh*16+k8*4+j
    int v = kh * 16 + lr;
    if (v < DV_) {
#pragma unroll
      for (int j = 0; j < 4; ++j) {
        int row = qh * 16 + k8 * 4 + j;
        float inv = 1.f / ssum[row];
        int tok = qt * 32 + row;
        ob[(size_t)(b * L_ + tok) * KP_ + h * DV_ + v] = f2bf(oacc[j] * inv);
      }
    }
  }
  if (h == H_ - 1) {                    // zero K-pad cols 200..223 for this q-tile
    for (int idx = tid; idx < 32 * (KP_ - DM_); idx += 256) {
      int row = idx / (KP_ - DM_), c = idx % (KP_ - DM_);
      ob[(size_t)(b * L_ + qt * 32 + row) * KP_ + DM_ + c] = 0;
    }
  }
}

// ------- x_out = LayerNorm(y + x_in) (unbiased var, eps on sigma); also writes bf16 xb ----
__global__ __launch_bounds__(256) void add_ln_kernel(
    const float* __restrict__ y, const float* __restrict__ xin,
    const float* __restrict__ a, const float* __restrict__ bpar,
    float* __restrict__ xout, u16* __restrict__ xb) {
  int t = blockIdx.x * 4 + (threadIdx.x >> 6);
  int lane = threadIdx.x & 63;
  const float* yr = y + (size_t)t * DM_;
  const float* xr = xin + (size_t)t * DM_;
  float z0 = yr[lane] + xr[lane];
  float z1 = yr[lane + 64] + xr[lane + 64];
  float z2 = yr[lane + 128] + xr[lane + 128];
  float z3 = (lane < 8) ? (yr[lane + 192] + xr[lane + 192]) : 0.f;
  float sum = wave_sum(z0 + z1 + z2 + z3);
  float mu = sum * (1.f / DM_);
  float d0 = z0 - mu, d1 = z1 - mu, d2 = z2 - mu;
  float d3 = (lane < 8) ? (z3 - mu) : 0.f;
  float ss = wave_sum(d0 * d0 + d1 * d1 + d2 * d2 + d3 * d3);
  float inv = 1.f / (sqrtf(ss * (1.f / (DM_ - 1))) + 1e-3f);
  float* xo = xout + (size_t)t * DM_;
  u16* xbr = xb + (size_t)t * KP_;
  float o0 = d0 * inv * a[lane] + bpar[lane];
  float o1 = d1 * inv * a[lane + 64] + bpar[lane + 64];
  float o2 = d2 * inv * a[lane + 128] + bpar[lane + 128];
  xo[lane] = o0;        xbr[lane] = f2bf(o0);
  xo[lane + 64] = o1;   xbr[lane + 64] = f2bf(o1);
  xo[lane + 128] = o2;  xbr[lane + 128] = f2bf(o2);
  if (lane < 8) {
    float o3 = d3 * inv * a[lane + 192] + bpar[lane + 192];
    xo[lane + 192] = o3;
    xbr[lane + 192] = f2bf(o3);
  } else if (lane < 32) {
    xbr[lane + 192] = 0;  // pad cols 200..223
  }
}

extern "C" void kernel_launch(void* const* d_in, const int* in_sizes, int n_in,
                              void* d_out, int out_size, void* d_ws, size_t ws_size,
                              hipStream_t stream) {
  const float* we       = (const float*)d_in[0];
  const float* ee       = (const float*)d_in[1];
  const float* te       = (const float*)d_in[2];
  const float* pt       = (const float*)d_in[3];
  const float* bias     = (const float*)d_in[4];
  const float* w_qs     = (const float*)d_in[5];
  const float* w_ks     = (const float*)d_in[6];
  const float* w_vs     = (const float*)d_in[7];
  const float* w_o      = (const float*)d_in[8];
  const float* ffn_w1   = (const float*)d_in[9];
  const float* ffn_b1   = (const float*)d_in[10];
  const float* ffn_w2   = (const float*)d_in[11];
  const float* ffn_b2   = (const float*)d_in[12];
  const float* ln_ffn_a = (const float*)d_in[13];
  const float* ln_ffn_b = (const float*)d_in[14];
  const float* ln_attn_a= (const float*)d_in[15];
  const float* ln_attn_b= (const float*)d_in[16];
  const int* wseq       = (const int*)d_in[17];
  const int* eseq       = (const int*)d_in[18];
  const int* tseq       = (const int*)d_in[19];
  const int* pseq       = (const int*)d_in[20];
  float* out = (float*)d_out;

  // ---- workspace layout (bytes), adaptive chunking ----
  char* p = (char*)d_ws;
  float* x  = (float*)p; p += (size_t)NTOK * DM_ * 4;           // 13,107,200
  u16* xb   = (u16*)p;   p += (size_t)NTOK * KP_ * 2;           //  7,340,032
  u16* W1b  = (u16*)p;   p += (size_t)NL_ * DFF_ * KP_ * 2;     //  1,075,200
  u16* W2b  = (u16*)p;   p += (size_t)NL_ * DM_ * DFF_ * 2;     //    960,000
  u16* Wqb  = (u16*)p;   p += (size_t)NL_ * QKVD * KP_ * 2;     //    806,400
  u16* Wob  = (u16*)p;   p += (size_t)NL_ * DM_ * KP_ * 2;      //    268,800
  char* S   = p;                                                // chunk scratch
  size_t fixedB = (size_t)(S - (char*)d_ws);
  // per-token scratch: region1 max(hb 1600B, Qh+Kh 1024B) + region2 (VTh 512 + ob 448)
  int NC = 1;
  while (NC < 16 && fixedB + (size_t)(NTOK / NC) * 2560 > ws_size) NC <<= 1;
  if (fixedB + (size_t)(NTOK / NC) * 2560 > ws_size) return;
  const int chunkTok = NTOK / NC;       // multiple of 1024
  const int bc       = B_ / NC;         // batches per chunk (>=2)

  u16* hb  = (u16*)S;                              // [chunkTok][800] bf16 (FFN)
  u16* Qh  = (u16*)S;                              // [bc*8][512][32] bf16 (aliases hb)
  u16* Kh  = Qh + (size_t)chunkTok * 256;          // [bc*8][512][32]
  char* R2 = S + (size_t)chunkTok * 1600;
  u16* VTh = (u16*)R2;                             // [bc*8][32][512]
  u16* ob  = VTh + (size_t)chunkTok * 256;         // [chunkTok][KP_]
  float* y = out;                                  // [NTOK][200] fp32, aliases d_out

  embed_kernel<<<NTOK / 4, 256, 0, stream>>>(we, ee, te, pt, bias, wseq, eseq, tseq, pseq,
                                             x, xb);
  {
    int n1 = NL_ * DFF_ * KP_;
    castpad_kernel<<<(n1 + 255) / 256, 256, 0, stream>>>(ffn_w1, W1b, NL_ * DFF_, DM_, KP_);
    int n2 = NL_ * DM_ * DFF_;
    castpad_kernel<<<(n2 + 255) / 256, 256, 0, stream>>>(ffn_w2, W2b, NL_ * DM_, DFF_, DFF_);
    int n3 = NL_ * QKVD * KP_;
    repack_qkv_kernel<<<(n3 + 255) / 256, 256, 0, stream>>>(w_qs, w_ks, w_vs, Wqb);
    int n4 = NL_ * DM_ * KP_;
    castpad_kernel<<<(n4 + 255) / 256, 256, 0, stream>>>(w_o, Wob, NL_ * DM_, DM_, KP_);
    int nv = bc * 8 * 7 * 512;
    zero_vtpad_kernel<<<(nv + 255) / 256, 256, 0, stream>>>(VTh, nv);
  }

  dim3 gF1(chunkTok / 128, (DFF_ + 127) / 128);            // 128-col tiles, M=800
  dim3 gF2(chunkTok / 128, (DM_ + 63) / 64);               // 64-col tiles,  M=200
  dim3 gQK(chunkTok / 128, (QKVD + 127) / 128);
  int nbh = bc * 8;
  int gAttn = nbh * (L_ / 32);                             // 1-D XCD-local grid

  for (int i = 0; i < NL_; ++i) {
    for (int c = 0; c < NC; ++c) {
      size_t t0 = (size_t)c * chunkTok;
      mfma_gemm<128, 1, 1, 1><<<gF1, 256, 0, stream>>>(xb + t0 * KP_,
          W1b + (size_t)i * DFF_ * KP_, ffn_b1 + i * DFF_, hb, DFF_, KP_);
      mfma_gemm<64, 1, 0, 0><<<gF2, 256, 0, stream>>>(hb,
          W2b + (size_t)i * DM_ * DFF_, ffn_b2 + i * DM_, y + t0 * DM_, DM_, DFF_);
      add_ln_kernel<<<chunkTok / 4, 256, 0, stream>>>(y + t0 * DM_, x + t0 * DM_,
          ln_ffn_a + i * DM_, ln_ffn_b + i * DM_, x + t0 * DM_, xb + t0 * KP_);
    }
    for (int c = 0; c < NC; ++c) {
      size_t t0 = (size_t)c * chunkTok;
      zero_qkpad_kernel<<<chunkTok * 8 / 256, 256, 0, stream>>>(Qh, Kh);
      mfma_gemm_qkv<<<gQK, 256, 0, stream>>>(xb + t0 * KP_,
          Wqb + (size_t)i * QKVD * KP_, Qh, Kh, VTh);
      attn_mfma3_kernel<<<gAttn, 256, 0, stream>>>(Qh, Kh, VTh, wseq + t0, ob, nbh);
      mfma_gemm<64, 0, 0, 0><<<gF2, 256, 0, stream>>>(ob,
          Wob + (size_t)i * DM_ * KP_, nullptr, y + t0 * DM_, DM_, KP_);
      add_ln_kernel<<<chunkTok / 4, 256, 0, stream>>>(y + t0 * DM_, x + t0 * DM_,
          ln_attn_a + i * DM_, ln_attn_b + i * DM_,
          ((i == NL_ - 1) ? out : x) + t0 * DM_, xb + t0 * KP_);
    }
  }
}